// Round 5
// baseline (376.473 us; speedup 1.0000x reference)
//
#include <hip/hip_runtime.h>
#include <hip/hip_bf16.h>
#include <math.h>
#include <stdint.h>

typedef __bf16 bf16x8 __attribute__((ext_vector_type(8)));
typedef __bf16 bf16x4 __attribute__((ext_vector_type(4)));
typedef float floatx4 __attribute__((ext_vector_type(4)));
typedef short shortx4 __attribute__((ext_vector_type(4)));

#define NQS   2048
#define NKVS  2048
#define NKV1  2049
#define DM    1024
#define NH    16
#define DHD   64
#define BATCH 2
#define ROWS  (BATCH * NQS)   // 4096

// async global->LDS, 16B per lane. LDS dest must be wave-uniform base + lane*16.
__device__ __forceinline__ void gld_lds16(const __bf16* gp, __bf16* lp) {
    __builtin_amdgcn_global_load_lds(
        (const __attribute__((address_space(1))) uint32_t*)(uintptr_t)gp,
        (__attribute__((address_space(3))) uint32_t*)(uintptr_t)lp,
        16, 0, 0);
}

// tanh-form GELU in exp2 domain
__device__ __forceinline__ float gelu_fast(float x) {
    const float u = x * x;
    const float e = __builtin_amdgcn_exp2f(x * (-2.3022077f + (-0.1029431f) * u));
    return x * __builtin_amdgcn_rcpf(1.0f + e);
}

// ---------------------------------------------------------------------------
// Fused LayerNorm for X and Y (f32 in) -> bf16 out.  grid 2*ROWS.
// ---------------------------------------------------------------------------
__global__ __launch_bounds__(256) void ln2_to_bf16(
    const float* __restrict__ X, const float* __restrict__ Y,
    const float* __restrict__ g0, const float* __restrict__ b0,
    const float* __restrict__ g0kv, const float* __restrict__ b0kv,
    __bf16* __restrict__ Xn, __bf16* __restrict__ Yn)
{
    int row = blockIdx.x;
    const float *src, *gamma, *beta; __bf16* dst;
    if (row < ROWS) { src = X; gamma = g0; beta = b0; dst = Xn; }
    else { row -= ROWS; src = Y; gamma = g0kv; beta = b0kv; dst = Yn; }
    const int tid = threadIdx.x;
    const float4 v = ((const float4*)(src + (size_t)row * DM))[tid];
    float s  = v.x + v.y + v.z + v.w;
    float sq = v.x * v.x + v.y * v.y + v.z * v.z + v.w * v.w;
    for (int off = 1; off < 64; off <<= 1) {
        s  += __shfl_xor(s, off);
        sq += __shfl_xor(sq, off);
    }
    __shared__ float red[8];
    const int wave = tid >> 6, lane = tid & 63;
    if (lane == 0) { red[wave * 2] = s; red[wave * 2 + 1] = sq; }
    __syncthreads();
    s  = red[0] + red[2] + red[4] + red[6];
    sq = red[1] + red[3] + red[5] + red[7];
    const float mu  = s * (1.0f / DM);
    const float var = sq * (1.0f / DM) - mu * mu;
    const float rs  = rsqrtf(var + 1e-5f);
    const float4 gv = ((const float4*)gamma)[tid];
    const float4 bv = ((const float4*)beta)[tid];
    bf16x4 o;
    o[0] = (__bf16)((v.x - mu) * rs * gv.x + bv.x);
    o[1] = (__bf16)((v.y - mu) * rs * gv.y + bv.y);
    o[2] = (__bf16)((v.z - mu) * rs * gv.z + bv.z);
    o[3] = (__bf16)((v.w - mu) * rs * gv.w + bv.w);
    *(bf16x4*)(dst + (size_t)row * DM + tid * 4) = o;
}

// ---------------------------------------------------------------------------
// Residual add + LN + FF2-accumulator init:
//   v = X + O;  out = v + bf2  (f32, FF2 atomics add onto this)
//   Hr = LN(v)  (bf16, FF1 input)
// ---------------------------------------------------------------------------
__global__ __launch_bounds__(256) void resid_ln(
    const float* __restrict__ X, const __bf16* __restrict__ O,
    const float* __restrict__ gamma, const float* __restrict__ beta,
    const float* __restrict__ bf2, float* __restrict__ out,
    __bf16* __restrict__ Hr)
{
    const int row = blockIdx.x;
    const int tid = threadIdx.x;
    const float4 xv = ((const float4*)(X + (size_t)row * DM))[tid];
    const bf16x4 ov = *(const bf16x4*)(O + (size_t)row * DM + tid * 4);
    float4 v;
    v.x = xv.x + (float)ov[0];
    v.y = xv.y + (float)ov[1];
    v.z = xv.z + (float)ov[2];
    v.w = xv.w + (float)ov[3];
    const float4 b2 = ((const float4*)bf2)[tid];
    float4 o0;
    o0.x = v.x + b2.x; o0.y = v.y + b2.y;
    o0.z = v.z + b2.z; o0.w = v.w + b2.w;
    ((float4*)(out + (size_t)row * DM))[tid] = o0;

    float s  = v.x + v.y + v.z + v.w;
    float sq = v.x * v.x + v.y * v.y + v.z * v.z + v.w * v.w;
    for (int off = 1; off < 64; off <<= 1) {
        s  += __shfl_xor(s, off);
        sq += __shfl_xor(sq, off);
    }
    __shared__ float red[8];
    const int wave = tid >> 6, lane = tid & 63;
    if (lane == 0) { red[wave * 2] = s; red[wave * 2 + 1] = sq; }
    __syncthreads();
    s  = red[0] + red[2] + red[4] + red[6];
    sq = red[1] + red[3] + red[5] + red[7];
    const float mu  = s * (1.0f / DM);
    const float var = sq * (1.0f / DM) - mu * mu;
    const float rs  = rsqrtf(var + 1e-5f);
    const float4 gv = ((const float4*)gamma)[tid];
    const float4 bv = ((const float4*)beta)[tid];
    bf16x4 o;
    o[0] = (__bf16)((v.x - mu) * rs * gv.x + bv.x);
    o[1] = (__bf16)((v.y - mu) * rs * gv.y + bv.y);
    o[2] = (__bf16)((v.z - mu) * rs * gv.z + bv.z);
    o[3] = (__bf16)((v.w - mu) * rs * gv.w + bv.w);
    *(bf16x4*)(Hr + (size_t)row * DM + tid * 4) = o;
}

// Fused transpose of the three 1024x1024 QKV weights (one launch, z picks W).
__global__ __launch_bounds__(256) void transpose3_f32_bf16(
    const float* __restrict__ Wq, const float* __restrict__ Wk,
    const float* __restrict__ Wv, __bf16* __restrict__ WqT,
    __bf16* __restrict__ WkT, __bf16* __restrict__ WvT)
{
    __shared__ float tile[32][33];
    const int z = blockIdx.z;
    const float* in = (z == 0) ? Wq : (z == 1) ? Wk : Wv;
    __bf16* out = (z == 0) ? WqT : (z == 1) ? WkT : WvT;
    const int c0 = blockIdx.x * 32, r0 = blockIdx.y * 32;
    const int tx = threadIdx.x, ty = threadIdx.y;
#pragma unroll
    for (int i = 0; i < 4; i++)
        tile[ty + i * 8][tx] = in[(size_t)(r0 + ty + i * 8) * DM + c0 + tx];
    __syncthreads();
#pragma unroll
    for (int i = 0; i < 4; i++)
        out[(size_t)(c0 + ty + i * 8) * DM + r0 + tx] = (__bf16)tile[tx][ty + i * 8];
}

// Fused transpose of W1 [1024][4096] and W2 [4096][1024] (z picks).
__global__ __launch_bounds__(256) void transpose_ffw(
    const float* __restrict__ W1, const float* __restrict__ W2,
    __bf16* __restrict__ W1T, __bf16* __restrict__ W2T)
{
    __shared__ float tile[32][33];
    const int z = blockIdx.z;
    const float* in; __bf16* out; int R, C, c0, r0;
    if (z == 0) { in = W1; out = W1T; R = DM; C = 4 * DM; c0 = blockIdx.x * 32; r0 = blockIdx.y * 32; }
    else        { in = W2; out = W2T; R = 4 * DM; C = DM; c0 = blockIdx.y * 32; r0 = blockIdx.x * 32; }
    const int tx = threadIdx.x, ty = threadIdx.y;
#pragma unroll
    for (int i = 0; i < 4; i++)
        tile[ty + i * 8][tx] = in[(size_t)(r0 + ty + i * 8) * C + c0 + tx];
    __syncthreads();
#pragma unroll
    for (int i = 0; i < 4; i++)
        out[(size_t)(c0 + ty + i * 8) * R + r0 + tx] = (__bf16)tile[tx][ty + i * 8];
}

// ---------------------------------------------------------------------------
// Fill null-K row (kv==2048) with null_k, and zero Vt pad columns [2048,2056)
// ---------------------------------------------------------------------------
__global__ __launch_bounds__(256) void fill_null(
    const float* __restrict__ null_k, __bf16* __restrict__ Kb,
    __bf16* __restrict__ Vt)
{
    const int i = blockIdx.x * 256 + threadIdx.x;
    if (i < BATCH * DM) {
        const int b = i >> 10, d = i & (DM - 1);
        Kb[((size_t)b * NKV1 + NKVS) * DM + d] = (__bf16)null_k[d];
    }
    if (i < BATCH * NH * DHD * 8) {  // 16384
        const int bhd = i >> 3, kvp = i & 7;
        Vt[(size_t)bhd * 2056 + 2048 + kvp] = (__bf16)0.0f;
    }
}

// ---------------------------------------------------------------------------
// 256x256-tile GEMM core (round-3 proven): 512 threads (8 waves, 2Mx4N),
// per-wave 128x64 output.  K as 32 subtiles of BK=32 in a 4-slot LDS ring
// (128 KiB), global_load_lds with 3 subtiles in flight, counted vmcnt(12),
// epilogue drain 8/4/0, two raw s_barriers per subtile.
// LDS source pre-swizzled: phys chunk j of row r holds logical j^(r&3).
// ---------------------------------------------------------------------------
__device__ __forceinline__ void g256_loop(
    const __bf16* __restrict__ A, const __bf16* __restrict__ Bt,
    int Kst, int kbeg, int m0, int n0,
    __bf16* sa, __bf16* sb, floatx4 (&acc)[8][4])
{
    const int tid = threadIdx.x, lane = tid & 63;
    const int g = lane >> 4, c = lane & 15;
    const int wave = tid >> 6;
    const int wm = wave >> 2, wn = wave & 3;

    const int r = tid >> 2, j = tid & 3;
    const int jx = (j ^ (r & 3)) * 8;            // swizzled source chunk (elems)
    const __bf16* Ag = A  + (size_t)(m0 + r) * Kst + kbeg + jx;
    const __bf16* Bg = Bt + (size_t)(n0 + r) * Kst + kbeg + jx;
    __bf16* la = sa + tid * 8;                   // byte offset tid*16
    __bf16* lb = sb + tid * 8;

#define G256_STAGE(ss, koff) do {                                          \
    gld_lds16(Ag + (koff),                      la + (ss) * 8192);         \
    gld_lds16(Ag + (size_t)128 * Kst + (koff),  la + (ss) * 8192 + 4096);  \
    gld_lds16(Bg + (koff),                      lb + (ss) * 8192);         \
    gld_lds16(Bg + (size_t)128 * Kst + (koff),  lb + (ss) * 8192 + 4096);  \
} while (0)

    // prologue: 3 subtiles in flight
    G256_STAGE(0, 0);
    G256_STAGE(1, 32);
    G256_STAGE(2, 64);

    const int ca = (c & 3) * 8;                  // read-side XOR (elems)
    const __bf16* ra = sa + (wm * 128 + c) * 32; // row base for A frags
    const __bf16* rb = sb + (wn * 64 + c) * 32;  // row base for B frags

    for (int s = 0; s < 32; s++) {
        if (s < 29) {
            G256_STAGE((s + 3) & 3, (s + 3) * 32);
            asm volatile("s_waitcnt vmcnt(12)" ::: "memory");
        } else if (s == 29) {
            asm volatile("s_waitcnt vmcnt(8)" ::: "memory");
        } else if (s == 30) {
            asm volatile("s_waitcnt vmcnt(4)" ::: "memory");
        } else {
            asm volatile("s_waitcnt vmcnt(0)" ::: "memory");
        }
        __builtin_amdgcn_sched_barrier(0);
        __builtin_amdgcn_s_barrier();            // all waves' subtile-s loads landed
        asm volatile("" ::: "memory");

        const int ss = (s & 3) * 8192;
        bf16x8 af[8], bfr[4];
#pragma unroll
        for (int i = 0; i < 8; i++)
            af[i] = *(const bf16x8*)(ra + ss + i * 512 + ((g * 8) ^ ca));
#pragma unroll
        for (int jj = 0; jj < 4; jj++)
            bfr[jj] = *(const bf16x8*)(rb + ss + jj * 512 + ((g * 8) ^ ca));

        __builtin_amdgcn_s_setprio(1);
#pragma unroll
        for (int i = 0; i < 8; i++)
#pragma unroll
            for (int jj = 0; jj < 4; jj++)
                acc[i][jj] = __builtin_amdgcn_mfma_f32_16x16x32_bf16(
                    af[i], bfr[jj], acc[i][jj], 0, 0, 0);
        __builtin_amdgcn_s_setprio(0);
        __builtin_amdgcn_sched_barrier(0);
        __builtin_amdgcn_s_barrier();            // reads of slot s done -> reusable
        asm volatile("" ::: "memory");
    }
#undef G256_STAGE
}

// XCD-bijective block swizzle: ntot = NX*NY blocks (ntot % 8 == 0); each XCD
// gets a contiguous chunk of logical tiles for L2 reuse.
template<int NX>
__device__ __forceinline__ void g256_decode(int bid, int ntot, int& m0, int& n0)
{
    const int cpx = ntot >> 3;
    const int l = (bid & 7) * cpx + (bid >> 3);
    m0 = (l / NX) * 256;
    n0 = (l % NX) * 256;
}

// MODE 0: bf16 flat [M][N] (+bias, optional GELU).
// MODE 5: split-K f32 atomicAdd into out[M][N] (blockIdx.z = K-slice of 1024;
//         out pre-initialized with Hres + bias by resid_ln).
template<int MODE, int ACT, int NX>
__global__ __launch_bounds__(512, 2) void g256(
    const __bf16* __restrict__ A, const __bf16* __restrict__ Bt,
    const float* __restrict__ bias, void* __restrict__ outp,
    int M, int N, int Kst)
{
    __shared__ __bf16 SA[4][256][32];
    __shared__ __bf16 SB[4][256][32];
    int m0, n0;
    g256_decode<NX>(blockIdx.x, NX * (M >> 8), m0, n0);
    const int kbeg = (MODE == 5) ? (blockIdx.z << 10) : 0;

    floatx4 acc[8][4] = {};
    g256_loop(A, Bt, Kst, kbeg, m0, n0, &SA[0][0][0], &SB[0][0][0], acc);

    const int tid = threadIdx.x, lane = tid & 63, wave = tid >> 6;
    const int g = lane >> 4, c = lane & 15;
    const int wm = wave >> 2, wn = wave & 3;

    __bf16* obf = (__bf16*)outp;
    float*  of  = (float*)outp;
#pragma unroll
    for (int i = 0; i < 8; i++) {
#pragma unroll
        for (int jj = 0; jj < 4; jj++) {
            const int row = m0 + wm * 128 + i * 16 + g * 4;
            const int col = n0 + wn * 64 + jj * 16 + c;
            const float bb = (MODE == 5) ? 0.0f : bias[col];
            float xs[4];
#pragma unroll
            for (int rr = 0; rr < 4; rr++) {
                float x = acc[i][jj][rr] + bb;
                if (ACT == 1) x = gelu_fast(x);
                xs[rr] = x;
            }
            if (MODE == 0) {
#pragma unroll
                for (int rr = 0; rr < 4; rr++)
                    obf[(size_t)(row + rr) * N + col] = (__bf16)xs[rr];
            } else if (MODE == 5) {
#pragma unroll
                for (int rr = 0; rr < 4; rr++)
                    atomicAdd(&of[(size_t)(row + rr) * N + col], xs[rr]);
            }
        }
    }
}

// Fused Q/K/V projection on the 256-tile core.  grid (64,1,3).
__global__ __launch_bounds__(512, 2) void g256qkv(
    const __bf16* __restrict__ Xn, const __bf16* __restrict__ Yn,
    const __bf16* __restrict__ WqT, const __bf16* __restrict__ WkT,
    const __bf16* __restrict__ WvT,
    const float* __restrict__ bq, const float* __restrict__ bk,
    const float* __restrict__ bv,
    __bf16* __restrict__ Qbf, __bf16* __restrict__ Kbf,
    __bf16* __restrict__ Vt)
{
    __shared__ __bf16 SA[4][256][32];
    __shared__ __bf16 SB[4][256][32];
    const int z = blockIdx.z;
    const __bf16* A    = (z == 0) ? Xn  : Yn;
    const __bf16* Bt   = (z == 0) ? WqT : (z == 1) ? WkT : WvT;
    const float*  bias = (z == 0) ? bq  : (z == 1) ? bk  : bv;

    int m0, n0;
    g256_decode<4>(blockIdx.x, 64, m0, n0);

    floatx4 acc[8][4] = {};
    g256_loop(A, Bt, DM, 0, m0, n0, &SA[0][0][0], &SB[0][0][0], acc);

    const int tid = threadIdx.x, lane = tid & 63, wave = tid >> 6;
    const int g = lane >> 4, c = lane & 15;
    const int wm = wave >> 2, wn = wave & 3;

#pragma unroll
    for (int i = 0; i < 8; i++) {
#pragma unroll
        for (int jj = 0; jj < 4; jj++) {
            const int row = m0 + wm * 128 + i * 16 + g * 4;
            const int col = n0 + wn * 64 + jj * 16 + c;
            const float bb = bias[col];
            float xs[4];
#pragma unroll
            for (int rr = 0; rr < 4; rr++) xs[rr] = acc[i][jj][rr] + bb;
            if (z == 0) {
#pragma unroll
                for (int rr = 0; rr < 4; rr++)
                    Qbf[(size_t)(row + rr) * DM + col] = (__bf16)xs[rr];
            } else if (z == 1) {
#pragma unroll
                for (int rr = 0; rr < 4; rr++) {
                    const int r2 = row + rr;
                    Kbf[(size_t)(r2 + (r2 >> 11)) * DM + col] = (__bf16)xs[rr];
                }
            } else {
                const int b  = row >> 11;
                const int kv = row & 2047;
                const size_t base =
                    ((size_t)((b * NH + (col >> 6)) * DHD + (col & 63))) * 2056 + kv;
                bf16x4 pk;
                pk[0] = (__bf16)xs[0]; pk[1] = (__bf16)xs[1];
                pk[2] = (__bf16)xs[2]; pk[3] = (__bf16)xs[3];
                *(bf16x4*)(Vt + base) = pk;
            }
        }
    }
}

// ---------------------------------------------------------------------------
// Flash attention (round-3 structure + v_perm pack + ones-MFMA denominator):
//  - 128 q/block, 32 q/wave; K/V via global_load_lds, XOR-swizzled source,
//    2-slot dbuf, one __syncthreads per tile.
//  - P pack: one v_perm_b32 per word (truncating bf16 pack).
//  - denominator: dacc[qt] += mfma(ones, pf) — no per-lane adds, no shuffles.
// ---------------------------------------------------------------------------
__global__ __launch_bounds__(256, 2) void attn_kernel(
    const __bf16* __restrict__ Q, const __bf16* __restrict__ Kb,
    const __bf16* __restrict__ Vt, __bf16* __restrict__ O)
{
    __shared__ __bf16 Ks[2][64][64];   // [kv][d]   16 KB
    __shared__ __bf16 Vs[2][64][64];   // [d][kv]   16 KB

    const int tid = threadIdx.x, lane = tid & 63, w = tid >> 6;
    const int g = lane >> 4, c = lane & 15;

    const int hw   = blockIdx.x;
    const int slot = hw >> 3;
    const int hb   = (hw & 7) | ((slot >> 4) << 3);   // 0..31
    const int h = hb & 15, b = hb >> 4;
    const int q0w = (slot & 15) * 128 + w * 32;

    const float QSC = 0.03125f * 1.44269504088896f;
    bf16x8 qf[2][2];
#pragma unroll
    for (int qt = 0; qt < 2; qt++) {
        const __bf16* Qbase = Q + ((size_t)(b * NQS + q0w + qt * 16 + c)) * DM + h * DHD;
        qf[qt][0] = *(const bf16x8*)(Qbase + g * 8);
        qf[qt][1] = *(const bf16x8*)(Qbase + 32 + g * 8);
#pragma unroll
        for (int e = 0; e < 8; e++) {
            qf[qt][0][e] = (__bf16)((float)qf[qt][0][e] * QSC);
            qf[qt][1][e] = (__bf16)((float)qf[qt][1][e] * QSC);
        }
    }

    // ones fragment for the denominator MFMA (bf16 1.0 = 0x3F80)
    shortx4 ones;
    ones[0] = ones[1] = ones[2] = ones[3] = (short)0x3F80;

    floatx4 dacc[2] = {};        // denominator accumulators (all rows equal)
    floatx4 oacc[2][4] = {};

    const int srow = tid >> 3;                    // LDS row 0..31 (and +32)
    const int schk = (tid & 7) ^ (srow & 7);      // swizzled 16B source chunk
    const __bf16* Kg  = Kb + (size_t)b * NKV1 * DM + h * DHD + schk * 8;
    const __bf16* Vg  = Vt + ((size_t)(b * NH + h) * DHD + srow) * 2056;
    const __bf16* Vg2 = Vg + (size_t)32 * 2056;
    const int vcol0 = schk * 8;

    auto stage = [&](int p, int kv0, bool tail) {
        __bf16* kd0 = &Ks[p][0][0]  + tid * 8;
        __bf16* kd1 = &Ks[p][32][0] + tid * 8;
        __bf16* vd0 = &Vs[p][0][0]  + tid * 8;
        __bf16* vd1 = &Vs[p][32][0] + tid * 8;
        if (!tail) {
            gld_lds16(Kg + (size_t)(kv0 + srow) * DM, kd0);
            gld_lds16(Kg + (size_t)(kv0 + srow + 32) * DM, kd1);
            gld_lds16(Vg + kv0 + vcol0, vd0);
            gld_lds16(Vg2 + kv0 + vcol0, vd1);
        } else {
            const int r0 = min(kv0 + srow, NKVS);
            const int r1 = min(kv0 + srow + 32, NKVS);
            const int vc = min(kv0 + vcol0, NKVS);
            gld_lds16(Kg + (size_t)r0 * DM, kd0);
            gld_lds16(Kg + (size_t)r1 * DM, kd1);
            gld_lds16(Vg + vc, vd0);
            gld_lds16(Vg2 + vc, vd1);
        }
    };

    auto compute = [&](int p, int kv0, bool tail) {
        floatx4 s[2][4];
#pragma unroll
        for (int qt = 0; qt < 2; qt++)
#pragma unroll
            for (int kvt = 0; kvt < 4; kvt++)
#pragma unroll
                for (int r = 0; r < 4; r++) s[qt][kvt][r] = -6.0f;

        const int sw = c & 7;
        __builtin_amdgcn_s_setprio(1);
#pragma unroll
        for (int kvt = 0; kvt < 4; kvt++) {
            const bf16x8 kf0 = *(const bf16x8*)&Ks[p][kvt * 16 + c][(g ^ sw) * 8];
            const bf16x8 kf1 = *(const bf16x8*)&Ks[p][kvt * 16 + c][((4 | g) ^ sw) * 8];
#pragma unroll
            for (int qt = 0; qt < 2; qt++) {
                s[qt][kvt] = __builtin_amdgcn_mfma_f32_16x16x32_bf16(kf0, qf[qt][0], s[qt][kvt], 0, 0, 0);
                s[qt][kvt] = __builtin_amdgcn_mfma_f32_16x16x32_bf16(kf1, qf[qt][1], s[qt][kvt], 0, 0, 0);
            }
        }
        __builtin_amdgcn_s_setprio(0);

        if (tail) {
#pragma unroll
            for (int qt = 0; qt < 2; qt++)
#pragma unroll
                for (int kvt = 0; kvt < 4; kvt++)
#pragma unroll
                    for (int r = 0; r < 4; r++)
                        if (kv0 + kvt * 16 + g * 4 + r >= NKV1) s[qt][kvt][r] = -1e30f;
        }

        // p = exp2(s); pack to bf16 by truncation via v_perm (1 op per word)
        shortx4 pf[2][4];
#pragma unroll
        for (int qt = 0; qt < 2; qt++)
#pragma unroll
            for (int kvt = 0; kvt < 4; kvt++) {
                const unsigned u0 = __builtin_bit_cast(unsigned, __builtin_amdgcn_exp2f(s[qt][kvt][0]));
                const unsigned u1 = __builtin_bit_cast(unsigned, __builtin_amdgcn_exp2f(s[qt][kvt][1]));
                const unsigned u2 = __builtin_bit_cast(unsigned, __builtin_amdgcn_exp2f(s[qt][kvt][2]));
                const unsigned u3 = __builtin_bit_cast(unsigned, __builtin_amdgcn_exp2f(s[qt][kvt][3]));
                unsigned pk0 = __builtin_amdgcn_perm(u1, u0, 0x07060302u);
                unsigned pk1 = __builtin_amdgcn_perm(u3, u2, 0x07060302u);
                unsigned long long pk = ((unsigned long long)pk1 << 32) | pk0;
                pf[qt][kvt] = __builtin_bit_cast(shortx4, pk);
            }

        // O^T += V^T P^T ; denominator via ones-row MFMA
        __builtin_amdgcn_s_setprio(1);
#pragma unroll
        for (int kvt = 0; kvt < 4; kvt++) {
            shortx4 vfr[4];
#pragma unroll
            for (int dt = 0; dt < 4; dt++) {
                const int slotp = (kvt * 2 + (g >> 1)) ^ sw;
                vfr[dt] = *(const shortx4*)&Vs[p][dt * 16 + c][slotp * 8 + (g & 1) * 4];
            }
#pragma unroll
            for (int dt = 0; dt < 4; dt++)
#pragma unroll
                for (int qt = 0; qt < 2; qt++)
                    oacc[qt][dt] = __builtin_amdgcn_mfma_f32_16x16x16bf16_1k(
                        vfr[dt], pf[qt][kvt], oacc[qt][dt], 0, 0, 0);
#pragma unroll
            for (int qt = 0; qt < 2; qt++)
                dacc[qt] = __builtin_amdgcn_mfma_f32_16x16x16bf16_1k(
                    ones, pf[qt][kvt], dacc[qt], 0, 0, 0);
        }
        __builtin_amdgcn_s_setprio(0);
    };

    // prologue: tile 0 -> buf 0
    stage(0, 0, false);
    __syncthreads();
    for (int it = 0; it < 32; it++) {
        stage((it + 1) & 1, (it + 1) * 64, it == 31);  // prefetch next tile
        compute(it & 1, it * 64, false);               // tiles 0..31 all full
        __syncthreads();                               // vmcnt(0)+barrier
    }
    compute(0, 2048, true);                            // tail tile in buf 0

#pragma unroll
    for (int qt = 0; qt < 2; qt++) {
        const float inv_l = 1.0f / dacc[qt][0];
        __bf16* Ob = O + ((size_t)(b * NQS + q0w + qt * 16 + c)) * DM + h * DHD;
#pragma unroll
        for (int dt = 0; dt < 4; dt++) {
            bf16x4 ob;
#pragma unroll
            for (int r = 0; r < 4; r++) ob[r] = (__bf16)(oacc[qt][dt][r] * inv_l);
            *(bf16x4*)(Ob + dt * 16 + g * 4) = ob;
        }
    }
}

// ---------------------------------------------------------------------------
extern "C" void kernel_launch(void* const* d_in, const int* in_sizes, int n_in,
                              void* d_out, int out_size, void* d_ws, size_t ws_size,
                              hipStream_t stream)
{
    const float* X      = (const float*)d_in[0];
    const float* Y      = (const float*)d_in[1];
    const float* Wq     = (const float*)d_in[2];
    const float* bq     = (const float*)d_in[3];
    const float* Wk     = (const float*)d_in[4];
    const float* bk     = (const float*)d_in[5];
    const float* Wv     = (const float*)d_in[6];
    const float* bv     = (const float*)d_in[7];
    const float* null_k = (const float*)d_in[8];
    const float* g0     = (const float*)d_in[9];
    const float* b0     = (const float*)d_in[10];
    const float* g0kv   = (const float*)d_in[11];
    const float* b0kv   = (const float*)d_in[12];
    const float* g1     = (const float*)d_in[13];
    const float* b1     = (const float*)d_in[14];
    const float* W1     = (const float*)d_in[15];
    const float* bf1    = (const float*)d_in[16];
    const float* W2     = (const float*)d_in[17];
    const float* bf2    = (const float*)d_in[18];
    float* out = (float*)d_out;

    // workspace carve (bytes).
    char* p = (char*)d_ws;
    __bf16* W2T  = (__bf16*)p; p += (size_t)4 * DM * DM * 2;          // [1024][4096]
    __bf16* Gbf  = (__bf16*)p; p += (size_t)ROWS * 4 * DM * 2;
    __bf16* Xn   = (__bf16*)p; p += (size_t)ROWS * DM * 2;
    __bf16* Yn   = (__bf16*)p; p += (size_t)ROWS * DM * 2;
    __bf16* WqT  = (__bf16*)p; p += (size_t)DM * DM * 2;
    __bf16* WkT  = (__bf16*)p; p += (size_t)DM * DM * 2;
    __bf16* WvT  = (__bf16*)p; p += (size_t)DM * DM * 2;
    __bf16* W1T  = (__bf16*)p; p += (size_t)4 * DM * DM * 2;          // [4096][1024]
    __bf16* Qbf  = (__bf16*)p; p += (size_t)ROWS * DM * 2;
    __bf16* Kbf  = (__bf16*)p; p += (size_t)BATCH * NKV1 * DM * 2;
    __bf16* Vt   = (__bf16*)p; p += (size_t)BATCH * NH * DHD * 2056 * 2;
    __bf16* Obf  = (__bf16*)p; p += (size_t)ROWS * DM * 2;
    __bf16* Hr   = (__bf16*)p; p += (size_t)ROWS * DM * 2;

    // 1. LayerNorms (fused X+Y, one launch)
    ln2_to_bf16<<<2 * ROWS, 256, 0, stream>>>(X, Y, g0, b0, g0kv, b0kv, Xn, Yn);

    // 2. weight transposes (f32 -> bf16, W^T), two launches total
    transpose3_f32_bf16<<<dim3(DM / 32, DM / 32, 3), dim3(32, 8), 0, stream>>>(
        Wq, Wk, Wv, WqT, WkT, WvT);
    transpose_ffw<<<dim3(128, 32, 2), dim3(32, 8), 0, stream>>>(W1, W2, W1T, W2T);

    // 3. fused Q/K/V projections on the 256-tile pipelined core
    g256qkv<<<dim3(64, 1, 3), 512, 0, stream>>>(
        Xn, Yn, WqT, WkT, WvT, bq, bk, bv, Qbf, Kbf, Vt);
    fill_null<<<64, 256, 0, stream>>>(null_k, Kbf, Vt);

    // 4. attention (dbuf + syncthreads, XCD-local heads, MFMA denominator)
    attn_kernel<<<dim3(512), 256, 0, stream>>>(Qbf, Kbf, Vt, Obf);

    // 5. residual + LN + FF2-accumulator init (out = Hres + bf2)
    resid_ln<<<ROWS, 256, 0, stream>>>(X, Obf, g1, b1, bf2, out, Hr);

    // 6. FFN: FF1 (bf16 out + GELU), FF2 split-K=4 atomicAdd into out
    g256<0, 1, 16><<<dim3(256), 512, 0, stream>>>(
        Hr, W1T, bf1, (void*)Gbf, ROWS, 4 * DM, DM);
    g256<5, 0, 4><<<dim3(64, 1, 4), 512, 0, stream>>>(
        Gbf, W2T, nullptr, (void*)out, ROWS, DM, 4 * DM);
}

// Round 6
// 353.020 us; speedup vs baseline: 1.0664x; 1.0664x over previous
//
#include <hip/hip_runtime.h>
#include <hip/hip_bf16.h>
#include <math.h>
#include <stdint.h>

typedef __bf16 bf16x8 __attribute__((ext_vector_type(8)));
typedef __bf16 bf16x4 __attribute__((ext_vector_type(4)));
typedef float floatx4 __attribute__((ext_vector_type(4)));
typedef short shortx4 __attribute__((ext_vector_type(4)));

#define NQS   2048
#define NKVS  2048
#define NKV1  2049
#define DM    1024
#define NH    16
#define DHD   64
#define BATCH 2
#define ROWS  (BATCH * NQS)   // 4096

// async global->LDS, 16B per lane. LDS dest must be wave-uniform base + lane*16.
__device__ __forceinline__ void gld_lds16(const __bf16* gp, __bf16* lp) {
    __builtin_amdgcn_global_load_lds(
        (const __attribute__((address_space(1))) uint32_t*)(uintptr_t)gp,
        (__attribute__((address_space(3))) uint32_t*)(uintptr_t)lp,
        16, 0, 0);
}

// tanh-form GELU in exp2 domain
__device__ __forceinline__ float gelu_fast(float x) {
    const float u = x * x;
    const float e = __builtin_amdgcn_exp2f(x * (-2.3022077f + (-0.1029431f) * u));
    return x * __builtin_amdgcn_rcpf(1.0f + e);
}

// ---------------------------------------------------------------------------
// Fused LayerNorm for X and Y (f32 in) -> bf16 out.  grid 2*ROWS.
// ---------------------------------------------------------------------------
__global__ __launch_bounds__(256) void ln2_to_bf16(
    const float* __restrict__ X, const float* __restrict__ Y,
    const float* __restrict__ g0, const float* __restrict__ b0,
    const float* __restrict__ g0kv, const float* __restrict__ b0kv,
    __bf16* __restrict__ Xn, __bf16* __restrict__ Yn)
{
    int row = blockIdx.x;
    const float *src, *gamma, *beta; __bf16* dst;
    if (row < ROWS) { src = X; gamma = g0; beta = b0; dst = Xn; }
    else { row -= ROWS; src = Y; gamma = g0kv; beta = b0kv; dst = Yn; }
    const int tid = threadIdx.x;
    const float4 v = ((const float4*)(src + (size_t)row * DM))[tid];
    float s  = v.x + v.y + v.z + v.w;
    float sq = v.x * v.x + v.y * v.y + v.z * v.z + v.w * v.w;
    for (int off = 1; off < 64; off <<= 1) {
        s  += __shfl_xor(s, off);
        sq += __shfl_xor(sq, off);
    }
    __shared__ float red[8];
    const int wave = tid >> 6, lane = tid & 63;
    if (lane == 0) { red[wave * 2] = s; red[wave * 2 + 1] = sq; }
    __syncthreads();
    s  = red[0] + red[2] + red[4] + red[6];
    sq = red[1] + red[3] + red[5] + red[7];
    const float mu  = s * (1.0f / DM);
    const float var = sq * (1.0f / DM) - mu * mu;
    const float rs  = rsqrtf(var + 1e-5f);
    const float4 gv = ((const float4*)gamma)[tid];
    const float4 bv = ((const float4*)beta)[tid];
    bf16x4 o;
    o[0] = (__bf16)((v.x - mu) * rs * gv.x + bv.x);
    o[1] = (__bf16)((v.y - mu) * rs * gv.y + bv.y);
    o[2] = (__bf16)((v.z - mu) * rs * gv.z + bv.z);
    o[3] = (__bf16)((v.w - mu) * rs * gv.w + bv.w);
    *(bf16x4*)(dst + (size_t)row * DM + tid * 4) = o;
}

// ---------------------------------------------------------------------------
// Residual add + LayerNorm: Hres = X + O (f32 out), Hr = LN(Hres) (bf16 out)
// ---------------------------------------------------------------------------
__global__ __launch_bounds__(256) void resid_ln(
    const float* __restrict__ X, const __bf16* __restrict__ O,
    const float* __restrict__ gamma, const float* __restrict__ beta,
    float* __restrict__ Hres, __bf16* __restrict__ Hr)
{
    const int row = blockIdx.x;
    const int tid = threadIdx.x;
    const float4 xv = ((const float4*)(X + (size_t)row * DM))[tid];
    const bf16x4 ov = *(const bf16x4*)(O + (size_t)row * DM + tid * 4);
    float4 v;
    v.x = xv.x + (float)ov[0];
    v.y = xv.y + (float)ov[1];
    v.z = xv.z + (float)ov[2];
    v.w = xv.w + (float)ov[3];
    ((float4*)(Hres + (size_t)row * DM))[tid] = v;

    float s  = v.x + v.y + v.z + v.w;
    float sq = v.x * v.x + v.y * v.y + v.z * v.z + v.w * v.w;
    for (int off = 1; off < 64; off <<= 1) {
        s  += __shfl_xor(s, off);
        sq += __shfl_xor(sq, off);
    }
    __shared__ float red[8];
    const int wave = tid >> 6, lane = tid & 63;
    if (lane == 0) { red[wave * 2] = s; red[wave * 2 + 1] = sq; }
    __syncthreads();
    s  = red[0] + red[2] + red[4] + red[6];
    sq = red[1] + red[3] + red[5] + red[7];
    const float mu  = s * (1.0f / DM);
    const float var = sq * (1.0f / DM) - mu * mu;
    const float rs  = rsqrtf(var + 1e-5f);
    const float4 gv = ((const float4*)gamma)[tid];
    const float4 bv = ((const float4*)beta)[tid];
    bf16x4 o;
    o[0] = (__bf16)((v.x - mu) * rs * gv.x + bv.x);
    o[1] = (__bf16)((v.y - mu) * rs * gv.y + bv.y);
    o[2] = (__bf16)((v.z - mu) * rs * gv.z + bv.z);
    o[3] = (__bf16)((v.w - mu) * rs * gv.w + bv.w);
    *(bf16x4*)(Hr + (size_t)row * DM + tid * 4) = o;
}

// Fused transpose of the three 1024x1024 QKV weights (one launch, z picks W).
__global__ __launch_bounds__(256) void transpose3_f32_bf16(
    const float* __restrict__ Wq, const float* __restrict__ Wk,
    const float* __restrict__ Wv, __bf16* __restrict__ WqT,
    __bf16* __restrict__ WkT, __bf16* __restrict__ WvT)
{
    __shared__ float tile[32][33];
    const int z = blockIdx.z;
    const float* in = (z == 0) ? Wq : (z == 1) ? Wk : Wv;
    __bf16* out = (z == 0) ? WqT : (z == 1) ? WkT : WvT;
    const int c0 = blockIdx.x * 32, r0 = blockIdx.y * 32;
    const int tx = threadIdx.x, ty = threadIdx.y;
#pragma unroll
    for (int i = 0; i < 4; i++)
        tile[ty + i * 8][tx] = in[(size_t)(r0 + ty + i * 8) * DM + c0 + tx];
    __syncthreads();
#pragma unroll
    for (int i = 0; i < 4; i++)
        out[(size_t)(c0 + ty + i * 8) * DM + r0 + tx] = (__bf16)tile[tx][ty + i * 8];
}

// Fused transpose of W1 [1024][4096] and W2 [4096][1024] (z picks).
__global__ __launch_bounds__(256) void transpose_ffw(
    const float* __restrict__ W1, const float* __restrict__ W2,
    __bf16* __restrict__ W1T, __bf16* __restrict__ W2T)
{
    __shared__ float tile[32][33];
    const int z = blockIdx.z;
    const float* in; __bf16* out; int R, C, c0, r0;
    if (z == 0) { in = W1; out = W1T; R = DM; C = 4 * DM; c0 = blockIdx.x * 32; r0 = blockIdx.y * 32; }
    else        { in = W2; out = W2T; R = 4 * DM; C = DM; c0 = blockIdx.y * 32; r0 = blockIdx.x * 32; }
    const int tx = threadIdx.x, ty = threadIdx.y;
#pragma unroll
    for (int i = 0; i < 4; i++)
        tile[ty + i * 8][tx] = in[(size_t)(r0 + ty + i * 8) * C + c0 + tx];
    __syncthreads();
#pragma unroll
    for (int i = 0; i < 4; i++)
        out[(size_t)(c0 + ty + i * 8) * R + r0 + tx] = (__bf16)tile[tx][ty + i * 8];
}

// ---------------------------------------------------------------------------
// Fill null-K row (kv==2048) with null_k, and zero Vt pad columns [2048,2056)
// ---------------------------------------------------------------------------
__global__ __launch_bounds__(256) void fill_null(
    const float* __restrict__ null_k, __bf16* __restrict__ Kb,
    __bf16* __restrict__ Vt)
{
    const int i = blockIdx.x * 256 + threadIdx.x;
    if (i < BATCH * DM) {
        const int b = i >> 10, d = i & (DM - 1);
        Kb[((size_t)b * NKV1 + NKVS) * DM + d] = (__bf16)null_k[d];
    }
    if (i < BATCH * NH * DHD * 8) {  // 16384
        const int bhd = i >> 3, kvp = i & 7;
        Vt[(size_t)bhd * 2056 + 2048 + kvp] = (__bf16)0.0f;
    }
}

// ---------------------------------------------------------------------------
// 256x256-tile GEMM core (round-3 proven): 512 threads (8 waves, 2Mx4N),
// per-wave 128x64 output.  K as 32 subtiles of BK=32 in a 4-slot LDS ring
// (128 KiB), global_load_lds with 3 subtiles in flight, counted vmcnt(12),
// epilogue drain 8/4/0, two raw s_barriers per subtile.
// LDS source pre-swizzled: phys chunk j of row r holds logical j^(r&3).
// ---------------------------------------------------------------------------
__device__ __forceinline__ void g256_loop(
    const __bf16* __restrict__ A, const __bf16* __restrict__ Bt,
    int Kst, int kbeg, int m0, int n0,
    __bf16* sa, __bf16* sb, floatx4 (&acc)[8][4])
{
    const int tid = threadIdx.x, lane = tid & 63;
    const int g = lane >> 4, c = lane & 15;
    const int wave = tid >> 6;
    const int wm = wave >> 2, wn = wave & 3;

    const int r = tid >> 2, j = tid & 3;
    const int jx = (j ^ (r & 3)) * 8;            // swizzled source chunk (elems)
    const __bf16* Ag = A  + (size_t)(m0 + r) * Kst + kbeg + jx;
    const __bf16* Bg = Bt + (size_t)(n0 + r) * Kst + kbeg + jx;
    __bf16* la = sa + tid * 8;                   // byte offset tid*16
    __bf16* lb = sb + tid * 8;

#define G256_STAGE(ss, koff) do {                                          \
    gld_lds16(Ag + (koff),                      la + (ss) * 8192);         \
    gld_lds16(Ag + (size_t)128 * Kst + (koff),  la + (ss) * 8192 + 4096);  \
    gld_lds16(Bg + (koff),                      lb + (ss) * 8192);         \
    gld_lds16(Bg + (size_t)128 * Kst + (koff),  lb + (ss) * 8192 + 4096);  \
} while (0)

    // prologue: 3 subtiles in flight
    G256_STAGE(0, 0);
    G256_STAGE(1, 32);
    G256_STAGE(2, 64);

    const int ca = (c & 3) * 8;                  // read-side XOR (elems)
    const __bf16* ra = sa + (wm * 128 + c) * 32; // row base for A frags
    const __bf16* rb = sb + (wn * 64 + c) * 32;  // row base for B frags

    for (int s = 0; s < 32; s++) {
        if (s < 29) {
            G256_STAGE((s + 3) & 3, (s + 3) * 32);
            asm volatile("s_waitcnt vmcnt(12)" ::: "memory");
        } else if (s == 29) {
            asm volatile("s_waitcnt vmcnt(8)" ::: "memory");
        } else if (s == 30) {
            asm volatile("s_waitcnt vmcnt(4)" ::: "memory");
        } else {
            asm volatile("s_waitcnt vmcnt(0)" ::: "memory");
        }
        __builtin_amdgcn_sched_barrier(0);
        __builtin_amdgcn_s_barrier();            // all waves' subtile-s loads landed
        asm volatile("" ::: "memory");

        const int ss = (s & 3) * 8192;
        bf16x8 af[8], bfr[4];
#pragma unroll
        for (int i = 0; i < 8; i++)
            af[i] = *(const bf16x8*)(ra + ss + i * 512 + ((g * 8) ^ ca));
#pragma unroll
        for (int jj = 0; jj < 4; jj++)
            bfr[jj] = *(const bf16x8*)(rb + ss + jj * 512 + ((g * 8) ^ ca));

        __builtin_amdgcn_s_setprio(1);
#pragma unroll
        for (int i = 0; i < 8; i++)
#pragma unroll
            for (int jj = 0; jj < 4; jj++)
                acc[i][jj] = __builtin_amdgcn_mfma_f32_16x16x32_bf16(
                    af[i], bfr[jj], acc[i][jj], 0, 0, 0);
        __builtin_amdgcn_s_setprio(0);
        __builtin_amdgcn_sched_barrier(0);
        __builtin_amdgcn_s_barrier();            // reads of slot s done -> reusable
        asm volatile("" ::: "memory");
    }
#undef G256_STAGE
}

// XCD-bijective block swizzle: ntot = NX*NY blocks (ntot % 8 == 0); each XCD
// gets a contiguous chunk of logical tiles for L2 reuse.
template<int NX>
__device__ __forceinline__ void g256_decode(int bid, int ntot, int& m0, int& n0)
{
    const int cpx = ntot >> 3;
    const int l = (bid & 7) * cpx + (bid >> 3);
    m0 = (l / NX) * 256;
    n0 = (l % NX) * 256;
}

// MODE 0: bf16 flat [M][N] (+bias, optional GELU).  MODE 4: split-K f32
// partials at [z][M][N] (blockIdx.z = K-slice of 1024).
template<int MODE, int ACT, int NX>
__global__ __launch_bounds__(512, 2) void g256(
    const __bf16* __restrict__ A, const __bf16* __restrict__ Bt,
    const float* __restrict__ bias, void* __restrict__ outp,
    int M, int N, int Kst)
{
    __shared__ __bf16 SA[4][256][32];
    __shared__ __bf16 SB[4][256][32];
    int m0, n0;
    g256_decode<NX>(blockIdx.x, NX * (M >> 8), m0, n0);
    const int kbeg = (MODE == 4) ? (blockIdx.z << 10) : 0;

    floatx4 acc[8][4] = {};
    g256_loop(A, Bt, Kst, kbeg, m0, n0, &SA[0][0][0], &SB[0][0][0], acc);

    const int tid = threadIdx.x, lane = tid & 63, wave = tid >> 6;
    const int g = lane >> 4, c = lane & 15;
    const int wm = wave >> 2, wn = wave & 3;

    __bf16* obf = (__bf16*)outp;
    float*  of  = (float*)outp;
#pragma unroll
    for (int i = 0; i < 8; i++) {
#pragma unroll
        for (int jj = 0; jj < 4; jj++) {
            const int row = m0 + wm * 128 + i * 16 + g * 4;
            const int col = n0 + wn * 64 + jj * 16 + c;
            const float bb = (MODE == 4) ? 0.0f : bias[col];
            float xs[4];
#pragma unroll
            for (int rr = 0; rr < 4; rr++) {
                float x = acc[i][jj][rr] + bb;
                if (ACT == 1) x = gelu_fast(x);
                xs[rr] = x;
            }
            if (MODE == 0) {
#pragma unroll
                for (int rr = 0; rr < 4; rr++)
                    obf[(size_t)(row + rr) * N + col] = (__bf16)xs[rr];
            } else if (MODE == 4) {
#pragma unroll
                for (int rr = 0; rr < 4; rr++)
                    of[((size_t)blockIdx.z * M + row + rr) * N + col] = xs[rr];
            }
        }
    }
}

// Fused Q/K/V projection on the 256-tile core.  grid (64,1,3).
__global__ __launch_bounds__(512, 2) void g256qkv(
    const __bf16* __restrict__ Xn, const __bf16* __restrict__ Yn,
    const __bf16* __restrict__ WqT, const __bf16* __restrict__ WkT,
    const __bf16* __restrict__ WvT,
    const float* __restrict__ bq, const float* __restrict__ bk,
    const float* __restrict__ bv,
    __bf16* __restrict__ Qbf, __bf16* __restrict__ Kbf,
    __bf16* __restrict__ Vt)
{
    __shared__ __bf16 SA[4][256][32];
    __shared__ __bf16 SB[4][256][32];
    const int z = blockIdx.z;
    const __bf16* A    = (z == 0) ? Xn  : Yn;
    const __bf16* Bt   = (z == 0) ? WqT : (z == 1) ? WkT : WvT;
    const float*  bias = (z == 0) ? bq  : (z == 1) ? bk  : bv;

    int m0, n0;
    g256_decode<4>(blockIdx.x, 64, m0, n0);

    floatx4 acc[8][4] = {};
    g256_loop(A, Bt, DM, 0, m0, n0, &SA[0][0][0], &SB[0][0][0], acc);

    const int tid = threadIdx.x, lane = tid & 63, wave = tid >> 6;
    const int g = lane >> 4, c = lane & 15;
    const int wm = wave >> 2, wn = wave & 3;

#pragma unroll
    for (int i = 0; i < 8; i++) {
#pragma unroll
        for (int jj = 0; jj < 4; jj++) {
            const int row = m0 + wm * 128 + i * 16 + g * 4;
            const int col = n0 + wn * 64 + jj * 16 + c;
            const float bb = bias[col];
            float xs[4];
#pragma unroll
            for (int rr = 0; rr < 4; rr++) xs[rr] = acc[i][jj][rr] + bb;
            if (z == 0) {
#pragma unroll
                for (int rr = 0; rr < 4; rr++)
                    Qbf[(size_t)(row + rr) * DM + col] = (__bf16)xs[rr];
            } else if (z == 1) {
#pragma unroll
                for (int rr = 0; rr < 4; rr++) {
                    const int r2 = row + rr;
                    Kbf[(size_t)(r2 + (r2 >> 11)) * DM + col] = (__bf16)xs[rr];
                }
            } else {
                const int b  = row >> 11;
                const int kv = row & 2047;
                const size_t base =
                    ((size_t)((b * NH + (col >> 6)) * DHD + (col & 63))) * 2056 + kv;
                bf16x4 pk;
                pk[0] = (__bf16)xs[0]; pk[1] = (__bf16)xs[1];
                pk[2] = (__bf16)xs[2]; pk[3] = (__bf16)xs[3];
                *(bf16x4*)(Vt + base) = pk;
            }
        }
    }
}

// ---------------------------------------------------------------------------
// FF2 split-K reduction: out = sum_z partials[z] + bias + Hres.  float4/thread.
// ---------------------------------------------------------------------------
__global__ __launch_bounds__(256) void ff2_reduce(
    const float* __restrict__ part, const float* __restrict__ bias,
    const float* __restrict__ Hres, float* __restrict__ out)
{
    const size_t f4 = (size_t)blockIdx.x * 256 + threadIdx.x;  // float4 index
    const int c4 = (int)(f4 & (DM / 4 - 1));
    const size_t stride4 = (size_t)ROWS * DM / 4;
    float4 a = ((const float4*)part)[f4];
    const float4 p1 = ((const float4*)part)[f4 + stride4];
    const float4 p2 = ((const float4*)part)[f4 + 2 * stride4];
    const float4 p3 = ((const float4*)part)[f4 + 3 * stride4];
    const float4 b  = ((const float4*)bias)[c4];
    const float4 hr = ((const float4*)Hres)[f4];
    a.x += p1.x + p2.x + p3.x + b.x + hr.x;
    a.y += p1.y + p2.y + p3.y + b.y + hr.y;
    a.z += p1.z + p2.z + p3.z + b.z + hr.z;
    a.w += p1.w + p2.w + p3.w + b.w + hr.w;
    ((float4*)out)[f4] = a;
}

// ---------------------------------------------------------------------------
// Flash attention v4: 128 q/block, 32 q/wave; gld_lds XOR-swizzled staging.
//  - 4-slot LDS ring (64 KB), TWO tiles staged + TWO tiles computed per
//    __syncthreads: halves barrier-drain count (17 vs 33).
//  - P pack via v_perm (truncating bf16); denominator via ones-MFMA.
//  - flat grid 512, XCD-aware decode (16 q-tiles of one (b,h) per XCD L2).
// ---------------------------------------------------------------------------
__global__ __launch_bounds__(256, 2) void attn_kernel(
    const __bf16* __restrict__ Q, const __bf16* __restrict__ Kb,
    const __bf16* __restrict__ Vt, __bf16* __restrict__ O)
{
    __shared__ __bf16 Ks[4][64][64];   // [kv][d]   32 KB
    __shared__ __bf16 Vs[4][64][64];   // [d][kv]   32 KB

    const int tid = threadIdx.x, lane = tid & 63, w = tid >> 6;
    const int g = lane >> 4, c = lane & 15;

    const int hw   = blockIdx.x;
    const int slot = hw >> 3;
    const int hb   = (hw & 7) | ((slot >> 4) << 3);   // 0..31
    const int h = hb & 15, b = hb >> 4;
    const int q0w = (slot & 15) * 128 + w * 32;

    const float QSC = 0.03125f * 1.44269504088896f;
    bf16x8 qf[2][2];
#pragma unroll
    for (int qt = 0; qt < 2; qt++) {
        const __bf16* Qbase = Q + ((size_t)(b * NQS + q0w + qt * 16 + c)) * DM + h * DHD;
        qf[qt][0] = *(const bf16x8*)(Qbase + g * 8);
        qf[qt][1] = *(const bf16x8*)(Qbase + 32 + g * 8);
#pragma unroll
        for (int e = 0; e < 8; e++) {
            qf[qt][0][e] = (__bf16)((float)qf[qt][0][e] * QSC);
            qf[qt][1][e] = (__bf16)((float)qf[qt][1][e] * QSC);
        }
    }

    // ones fragment for the denominator MFMA (bf16 1.0 = 0x3F80)
    shortx4 ones;
    ones[0] = ones[1] = ones[2] = ones[3] = (short)0x3F80;

    floatx4 dacc[2] = {};        // denominator accumulators (rows identical)
    floatx4 oacc[2][4] = {};

    const int srow = tid >> 3;                    // LDS row 0..31 (and +32)
    const int schk = (tid & 7) ^ (srow & 7);      // swizzled 16B source chunk
    const __bf16* Kg  = Kb + (size_t)b * NKV1 * DM + h * DHD + schk * 8;
    const __bf16* Vg  = Vt + ((size_t)(b * NH + h) * DHD + srow) * 2056;
    const __bf16* Vg2 = Vg + (size_t)32 * 2056;
    const int vcol0 = schk * 8;

    auto stage = [&](int p, int kv0, bool tail) {
        __bf16* kd0 = &Ks[p][0][0]  + tid * 8;
        __bf16* kd1 = &Ks[p][32][0] + tid * 8;
        __bf16* vd0 = &Vs[p][0][0]  + tid * 8;
        __bf16* vd1 = &Vs[p][32][0] + tid * 8;
        if (!tail) {
            gld_lds16(Kg + (size_t)(kv0 + srow) * DM, kd0);
            gld_lds16(Kg + (size_t)(kv0 + srow + 32) * DM, kd1);
            gld_lds16(Vg + kv0 + vcol0, vd0);
            gld_lds16(Vg2 + kv0 + vcol0, vd1);
        } else {
            const int r0 = min(kv0 + srow, NKVS);
            const int r1 = min(kv0 + srow + 32, NKVS);
            const int vc = min(kv0 + vcol0, NKVS);
            gld_lds16(Kg + (size_t)r0 * DM, kd0);
            gld_lds16(Kg + (size_t)r1 * DM, kd1);
            gld_lds16(Vg + vc, vd0);
            gld_lds16(Vg2 + vc, vd1);
        }
    };

    auto compute = [&](int p, int kv0, bool tail) {
        floatx4 s[2][4];
#pragma unroll
        for (int qt = 0; qt < 2; qt++)
#pragma unroll
            for (int kvt = 0; kvt < 4; kvt++)
#pragma unroll
                for (int r = 0; r < 4; r++) s[qt][kvt][r] = -6.0f;

        const int sw = c & 7;
        __builtin_amdgcn_s_setprio(1);
#pragma unroll
        for (int kvt = 0; kvt < 4; kvt++) {
            const bf16x8 kf0 = *(const bf16x8*)&Ks[p][kvt * 16 + c][(g ^ sw) * 8];
            const bf16x8 kf1 = *(const bf16x8*)&Ks[p][kvt * 16 + c][((4 | g) ^ sw) * 8];
#pragma unroll
            for (int qt = 0; qt < 2; qt++) {
                s[qt][kvt] = __builtin_amdgcn_mfma_f32_16x16x32_bf16(kf0, qf[qt][0], s[qt][kvt], 0, 0, 0);
                s[qt][kvt] = __builtin_amdgcn_mfma_f32_16x16x32_bf16(kf1, qf[qt][1], s[qt][kvt], 0, 0, 0);
            }
        }
        __builtin_amdgcn_s_setprio(0);

        if (tail) {
#pragma unroll
            for (int qt = 0; qt < 2; qt++)
#pragma unroll
                for (int kvt = 0; kvt < 4; kvt++)
#pragma unroll
                    for (int r = 0; r < 4; r++)
                        if (kv0 + kvt * 16 + g * 4 + r >= NKV1) s[qt][kvt][r] = -1e30f;
        }

        // p = exp2(s); pack to bf16 by truncation via v_perm (1 op per word)
        shortx4 pf[2][4];
#pragma unroll
        for (int qt = 0; qt < 2; qt++)
#pragma unroll
            for (int kvt = 0; kvt < 4; kvt++) {
                const unsigned u0 = __builtin_bit_cast(unsigned, __builtin_amdgcn_exp2f(s[qt][kvt][0]));
                const unsigned u1 = __builtin_bit_cast(unsigned, __builtin_amdgcn_exp2f(s[qt][kvt][1]));
                const unsigned u2 = __builtin_bit_cast(unsigned, __builtin_amdgcn_exp2f(s[qt][kvt][2]));
                const unsigned u3 = __builtin_bit_cast(unsigned, __builtin_amdgcn_exp2f(s[qt][kvt][3]));
                unsigned pk0 = __builtin_amdgcn_perm(u1, u0, 0x07060302u);
                unsigned pk1 = __builtin_amdgcn_perm(u3, u2, 0x07060302u);
                unsigned long long pk = ((unsigned long long)pk1 << 32) | pk0;
                pf[qt][kvt] = __builtin_bit_cast(shortx4, pk);
            }

        // O^T += V^T P^T ; denominator via ones-row MFMA
        __builtin_amdgcn_s_setprio(1);
#pragma unroll
        for (int kvt = 0; kvt < 4; kvt++) {
            shortx4 vfr[4];
#pragma unroll
            for (int dt = 0; dt < 4; dt++) {
                const int slotp = (kvt * 2 + (g >> 1)) ^ sw;
                vfr[dt] = *(const shortx4*)&Vs[p][dt * 16 + c][slotp * 8 + (g & 1) * 4];
            }
#pragma unroll
            for (int dt = 0; dt < 4; dt++)
#pragma unroll
                for (int qt = 0; qt < 2; qt++)
                    oacc[qt][dt] = __builtin_amdgcn_mfma_f32_16x16x16bf16_1k(
                        vfr[dt], pf[qt][kvt], oacc[qt][dt], 0, 0, 0);
#pragma unroll
            for (int qt = 0; qt < 2; qt++)
                dacc[qt] = __builtin_amdgcn_mfma_f32_16x16x16bf16_1k(
                    ones, pf[qt][kvt], dacc[qt], 0, 0, 0);
        }
        __builtin_amdgcn_s_setprio(0);
    };

    // 4-slot ring, 2 tiles per barrier period.  Tiles 0..32 (32 = tail).
    stage(0, 0, false);
    stage(1, 64, false);
    __syncthreads();
    for (int it = 0; it < 32; it += 2) {
        stage((it + 2) & 3, (it + 2) * 64, (it + 2) == 32);
        if (it + 3 <= 32) stage((it + 3) & 3, (it + 3) * 64, false);
        compute(it & 3, it * 64, false);
        compute((it + 1) & 3, (it + 1) * 64, false);
        __syncthreads();                 // staged tiles visible; reads done
    }
    compute(0, 2048, true);              // tail tile (32) in slot 0

#pragma unroll
    for (int qt = 0; qt < 2; qt++) {
        const float inv_l = 1.0f / dacc[qt][0];
        __bf16* Ob = O + ((size_t)(b * NQS + q0w + qt * 16 + c)) * DM + h * DHD;
#pragma unroll
        for (int dt = 0; dt < 4; dt++) {
            bf16x4 ob;
#pragma unroll
            for (int r = 0; r < 4; r++) ob[r] = (__bf16)(oacc[qt][dt][r] * inv_l);
            *(bf16x4*)(Ob + dt * 16 + g * 4) = ob;
        }
    }
}

// ---------------------------------------------------------------------------
extern "C" void kernel_launch(void* const* d_in, const int* in_sizes, int n_in,
                              void* d_out, int out_size, void* d_ws, size_t ws_size,
                              hipStream_t stream)
{
    const float* X      = (const float*)d_in[0];
    const float* Y      = (const float*)d_in[1];
    const float* Wq     = (const float*)d_in[2];
    const float* bq     = (const float*)d_in[3];
    const float* Wk     = (const float*)d_in[4];
    const float* bk     = (const float*)d_in[5];
    const float* Wv     = (const float*)d_in[6];
    const float* bv     = (const float*)d_in[7];
    const float* null_k = (const float*)d_in[8];
    const float* g0     = (const float*)d_in[9];
    const float* b0     = (const float*)d_in[10];
    const float* g0kv   = (const float*)d_in[11];
    const float* b0kv   = (const float*)d_in[12];
    const float* g1     = (const float*)d_in[13];
    const float* b1     = (const float*)d_in[14];
    const float* W1     = (const float*)d_in[15];
    const float* bf1    = (const float*)d_in[16];
    const float* W2     = (const float*)d_in[17];
    const float* bf2    = (const float*)d_in[18];
    float* out = (float*)d_out;

    // workspace carve (bytes).  Persistent-through-FF2 buffers FIRST so the
    // tail region (dead by FF2 time) can be reused for split-K partials.
    char* p = (char*)d_ws;
    __bf16* W2T  = (__bf16*)p; p += (size_t)4 * DM * DM * 2;          // [1024][4096]
    float*  Hres = (float*)p;  p += (size_t)ROWS * DM * 4;
    __bf16* Gbf  = (__bf16*)p; p += (size_t)ROWS * 4 * DM * 2;
    char* scratch = p;                                                // dead by FF2
    __bf16* Xn   = (__bf16*)p; p += (size_t)ROWS * DM * 2;
    __bf16* Yn   = (__bf16*)p; p += (size_t)ROWS * DM * 2;
    __bf16* WqT  = (__bf16*)p; p += (size_t)DM * DM * 2;
    __bf16* WkT  = (__bf16*)p; p += (size_t)DM * DM * 2;
    __bf16* WvT  = (__bf16*)p; p += (size_t)DM * DM * 2;
    __bf16* W1T  = (__bf16*)p; p += (size_t)4 * DM * DM * 2;          // [4096][1024]
    __bf16* Qbf  = (__bf16*)p; p += (size_t)ROWS * DM * 2;
    __bf16* Kbf  = (__bf16*)p; p += (size_t)BATCH * NKV1 * DM * 2;
    __bf16* Vt   = (__bf16*)p; p += (size_t)BATCH * NH * DHD * 2056 * 2;
    __bf16* Obf  = (__bf16*)p; p += (size_t)ROWS * DM * 2;
    __bf16* Hr   = (__bf16*)p; p += (size_t)ROWS * DM * 2;
    float* Part  = (float*)scratch;  // FF2 partials: 4 x ROWS x DM f32 = 67 MB

    // 1. LayerNorms (fused X+Y, one launch)
    ln2_to_bf16<<<2 * ROWS, 256, 0, stream>>>(X, Y, g0, b0, g0kv, b0kv, Xn, Yn);

    // 2. weight transposes (f32 -> bf16, W^T), two launches total
    transpose3_f32_bf16<<<dim3(DM / 32, DM / 32, 3), dim3(32, 8), 0, stream>>>(
        Wq, Wk, Wv, WqT, WkT, WvT);
    transpose_ffw<<<dim3(128, 32, 2), dim3(32, 8), 0, stream>>>(W1, W2, W1T, W2T);

    // 3. fused Q/K/V projections on the 256-tile pipelined core
    g256qkv<<<dim3(64, 1, 3), 512, 0, stream>>>(
        Xn, Yn, WqT, WkT, WvT, bq, bk, bv, Qbf, Kbf, Vt);
    fill_null<<<64, 256, 0, stream>>>(null_k, Kbf, Vt);

    // 4. attention (4-slot ring, 2 tiles/barrier, XCD-local heads)
    attn_kernel<<<dim3(512), 256, 0, stream>>>(Qbf, Kbf, Vt, Obf);

    // 5. residual + LN
    resid_ln<<<ROWS, 256, 0, stream>>>(X, Obf, g1, b1, Hres, Hr);

    // 6. FFN: FF1 (bf16 + GELU), FF2 split-K=4 partials, then reduce
    g256<0, 1, 16><<<dim3(256), 512, 0, stream>>>(
        Hr, W1T, bf1, (void*)Gbf, ROWS, 4 * DM, DM);
    g256<4, 0, 4><<<dim3(64, 1, 4), 512, 0, stream>>>(
        Gbf, W2T, bf2, (void*)Part, ROWS, DM, 4 * DM);
    ff2_reduce<<<ROWS * DM / 1024, 256, 0, stream>>>(Part, bf2, Hres, out);
}

// Round 7
// 342.006 us; speedup vs baseline: 1.1008x; 1.0322x over previous
//
#include <hip/hip_runtime.h>
#include <hip/hip_bf16.h>
#include <math.h>
#include <stdint.h>

typedef __bf16 bf16x8 __attribute__((ext_vector_type(8)));
typedef __bf16 bf16x4 __attribute__((ext_vector_type(4)));
typedef float floatx4 __attribute__((ext_vector_type(4)));
typedef short shortx4 __attribute__((ext_vector_type(4)));

#define NQS   2048
#define NKVS  2048
#define NKV1  2049
#define DM    1024
#define NH    16
#define DHD   64
#define BATCH 2
#define ROWS  (BATCH * NQS)   // 4096

// async global->LDS, 16B per lane. LDS dest must be wave-uniform base + lane*16.
__device__ __forceinline__ void gld_lds16(const __bf16* gp, __bf16* lp) {
    __builtin_amdgcn_global_load_lds(
        (const __attribute__((address_space(1))) uint32_t*)(uintptr_t)gp,
        (__attribute__((address_space(3))) uint32_t*)(uintptr_t)lp,
        16, 0, 0);
}

// tanh-form GELU in exp2 domain
__device__ __forceinline__ float gelu_fast(float x) {
    const float u = x * x;
    const float e = __builtin_amdgcn_exp2f(x * (-2.3022077f + (-0.1029431f) * u));
    return x * __builtin_amdgcn_rcpf(1.0f + e);
}

// ---------------------------------------------------------------------------
// Fused LayerNorm for X and Y (f32 in) -> bf16 out.  grid 2*ROWS.
// ---------------------------------------------------------------------------
__global__ __launch_bounds__(256) void ln2_to_bf16(
    const float* __restrict__ X, const float* __restrict__ Y,
    const float* __restrict__ g0, const float* __restrict__ b0,
    const float* __restrict__ g0kv, const float* __restrict__ b0kv,
    __bf16* __restrict__ Xn, __bf16* __restrict__ Yn)
{
    int row = blockIdx.x;
    const float *src, *gamma, *beta; __bf16* dst;
    if (row < ROWS) { src = X; gamma = g0; beta = b0; dst = Xn; }
    else { row -= ROWS; src = Y; gamma = g0kv; beta = b0kv; dst = Yn; }
    const int tid = threadIdx.x;
    const float4 v = ((const float4*)(src + (size_t)row * DM))[tid];
    float s  = v.x + v.y + v.z + v.w;
    float sq = v.x * v.x + v.y * v.y + v.z * v.z + v.w * v.w;
    for (int off = 1; off < 64; off <<= 1) {
        s  += __shfl_xor(s, off);
        sq += __shfl_xor(sq, off);
    }
    __shared__ float red[8];
    const int wave = tid >> 6, lane = tid & 63;
    if (lane == 0) { red[wave * 2] = s; red[wave * 2 + 1] = sq; }
    __syncthreads();
    s  = red[0] + red[2] + red[4] + red[6];
    sq = red[1] + red[3] + red[5] + red[7];
    const float mu  = s * (1.0f / DM);
    const float var = sq * (1.0f / DM) - mu * mu;
    const float rs  = rsqrtf(var + 1e-5f);
    const float4 gv = ((const float4*)gamma)[tid];
    const float4 bv = ((const float4*)beta)[tid];
    bf16x4 o;
    o[0] = (__bf16)((v.x - mu) * rs * gv.x + bv.x);
    o[1] = (__bf16)((v.y - mu) * rs * gv.y + bv.y);
    o[2] = (__bf16)((v.z - mu) * rs * gv.z + bv.z);
    o[3] = (__bf16)((v.w - mu) * rs * gv.w + bv.w);
    *(bf16x4*)(dst + (size_t)row * DM + tid * 4) = o;
}

// ---------------------------------------------------------------------------
// Residual add + LayerNorm: Hres = X + O (f32 out), Hr = LN(Hres) (bf16 out)
// ---------------------------------------------------------------------------
__global__ __launch_bounds__(256) void resid_ln(
    const float* __restrict__ X, const __bf16* __restrict__ O,
    const float* __restrict__ gamma, const float* __restrict__ beta,
    float* __restrict__ Hres, __bf16* __restrict__ Hr)
{
    const int row = blockIdx.x;
    const int tid = threadIdx.x;
    const float4 xv = ((const float4*)(X + (size_t)row * DM))[tid];
    const bf16x4 ov = *(const bf16x4*)(O + (size_t)row * DM + tid * 4);
    float4 v;
    v.x = xv.x + (float)ov[0];
    v.y = xv.y + (float)ov[1];
    v.z = xv.z + (float)ov[2];
    v.w = xv.w + (float)ov[3];
    ((float4*)(Hres + (size_t)row * DM))[tid] = v;

    float s  = v.x + v.y + v.z + v.w;
    float sq = v.x * v.x + v.y * v.y + v.z * v.z + v.w * v.w;
    for (int off = 1; off < 64; off <<= 1) {
        s  += __shfl_xor(s, off);
        sq += __shfl_xor(sq, off);
    }
    __shared__ float red[8];
    const int wave = tid >> 6, lane = tid & 63;
    if (lane == 0) { red[wave * 2] = s; red[wave * 2 + 1] = sq; }
    __syncthreads();
    s  = red[0] + red[2] + red[4] + red[6];
    sq = red[1] + red[3] + red[5] + red[7];
    const float mu  = s * (1.0f / DM);
    const float var = sq * (1.0f / DM) - mu * mu;
    const float rs  = rsqrtf(var + 1e-5f);
    const float4 gv = ((const float4*)gamma)[tid];
    const float4 bv = ((const float4*)beta)[tid];
    bf16x4 o;
    o[0] = (__bf16)((v.x - mu) * rs * gv.x + bv.x);
    o[1] = (__bf16)((v.y - mu) * rs * gv.y + bv.y);
    o[2] = (__bf16)((v.z - mu) * rs * gv.z + bv.z);
    o[3] = (__bf16)((v.w - mu) * rs * gv.w + bv.w);
    *(bf16x4*)(Hr + (size_t)row * DM + tid * 4) = o;
}

// Fused transpose of the three 1024x1024 QKV weights (one launch, z picks W).
__global__ __launch_bounds__(256) void transpose3_f32_bf16(
    const float* __restrict__ Wq, const float* __restrict__ Wk,
    const float* __restrict__ Wv, __bf16* __restrict__ WqT,
    __bf16* __restrict__ WkT, __bf16* __restrict__ WvT)
{
    __shared__ float tile[32][33];
    const int z = blockIdx.z;
    const float* in = (z == 0) ? Wq : (z == 1) ? Wk : Wv;
    __bf16* out = (z == 0) ? WqT : (z == 1) ? WkT : WvT;
    const int c0 = blockIdx.x * 32, r0 = blockIdx.y * 32;
    const int tx = threadIdx.x, ty = threadIdx.y;
#pragma unroll
    for (int i = 0; i < 4; i++)
        tile[ty + i * 8][tx] = in[(size_t)(r0 + ty + i * 8) * DM + c0 + tx];
    __syncthreads();
#pragma unroll
    for (int i = 0; i < 4; i++)
        out[(size_t)(c0 + ty + i * 8) * DM + r0 + tx] = (__bf16)tile[tx][ty + i * 8];
}

// Fused transpose of W1 [1024][4096] and W2 [4096][1024] (z picks).
__global__ __launch_bounds__(256) void transpose_ffw(
    const float* __restrict__ W1, const float* __restrict__ W2,
    __bf16* __restrict__ W1T, __bf16* __restrict__ W2T)
{
    __shared__ float tile[32][33];
    const int z = blockIdx.z;
    const float* in; __bf16* out; int R, C, c0, r0;
    if (z == 0) { in = W1; out = W1T; R = DM; C = 4 * DM; c0 = blockIdx.x * 32; r0 = blockIdx.y * 32; }
    else        { in = W2; out = W2T; R = 4 * DM; C = DM; c0 = blockIdx.y * 32; r0 = blockIdx.x * 32; }
    const int tx = threadIdx.x, ty = threadIdx.y;
#pragma unroll
    for (int i = 0; i < 4; i++)
        tile[ty + i * 8][tx] = in[(size_t)(r0 + ty + i * 8) * C + c0 + tx];
    __syncthreads();
#pragma unroll
    for (int i = 0; i < 4; i++)
        out[(size_t)(c0 + ty + i * 8) * R + r0 + tx] = (__bf16)tile[tx][ty + i * 8];
}

// ---------------------------------------------------------------------------
// Fill null-K row (kv==2048) with null_k, and zero Vt pad columns [2048,2056)
// ---------------------------------------------------------------------------
__global__ __launch_bounds__(256) void fill_null(
    const float* __restrict__ null_k, __bf16* __restrict__ Kb,
    __bf16* __restrict__ Vt)
{
    const int i = blockIdx.x * 256 + threadIdx.x;
    if (i < BATCH * DM) {
        const int b = i >> 10, d = i & (DM - 1);
        Kb[((size_t)b * NKV1 + NKVS) * DM + d] = (__bf16)null_k[d];
    }
    if (i < BATCH * NH * DHD * 8) {  // 16384
        const int bhd = i >> 3, kvp = i & 7;
        Vt[(size_t)bhd * 2056 + 2048 + kvp] = (__bf16)0.0f;
    }
}

// ---------------------------------------------------------------------------
// 256x256-tile GEMM core, 8-phase-style schedule (m201 template adapted):
// 512 threads (8 waves, 2Mx4N), per-wave 128x64 output.  K as 32 subtiles of
// BK=32 in a 4-slot LDS ring (128 KiB), global_load_lds, 3 subtiles ahead.
// Per subtile: vmcnt(8) gate + barrier, then 4 PHASES of
//   {2-3 ds_read ; 1 stage-piece gld_lds ; s_barrier ; lgkmcnt(0) ;
//    setprio(1) ; 8 MFMA (one 32-row quadrant) ; setprio(0)}
// so one wave's MFMA cluster hides the other's ds_reads/stage issue.
// LDS source pre-swizzled: phys chunk j of row r holds logical j^(r&3).
// ---------------------------------------------------------------------------
__device__ __forceinline__ void g256_loop(
    const __bf16* __restrict__ A, const __bf16* __restrict__ Bt,
    int Kst, int kbeg, int m0, int n0,
    __bf16* sa, __bf16* sb, floatx4 (&acc)[8][4])
{
    const int tid = threadIdx.x, lane = tid & 63;
    const int g = lane >> 4, c = lane & 15;
    const int wave = tid >> 6;
    const int wm = wave >> 2, wn = wave & 3;

    const int r = tid >> 2, j = tid & 3;
    const int jx = (j ^ (r & 3)) * 8;            // swizzled source chunk (elems)
    const __bf16* Ag = A  + (size_t)(m0 + r) * Kst + kbeg + jx;
    const __bf16* Bg = Bt + (size_t)(n0 + r) * Kst + kbeg + jx;
    __bf16* la = sa + tid * 8;                   // byte offset tid*16
    __bf16* lb = sb + tid * 8;

#define G256_STAGE(ss, koff) do {                                          \
    gld_lds16(Ag + (koff),                      la + (ss) * 8192);         \
    gld_lds16(Ag + (size_t)128 * Kst + (koff),  la + (ss) * 8192 + 4096);  \
    gld_lds16(Bg + (koff),                      lb + (ss) * 8192);         \
    gld_lds16(Bg + (size_t)128 * Kst + (koff),  lb + (ss) * 8192 + 4096);  \
} while (0)

    // prologue: 3 subtiles in flight
    G256_STAGE(0, 0);
    G256_STAGE(1, 32);
    G256_STAGE(2, 64);

    const int ca = (c & 3) * 8;                  // read-side XOR (elems)
    const __bf16* ra = sa + (wm * 128 + c) * 32; // row base for A frags
    const __bf16* rb = sb + (wn * 64 + c) * 32;  // row base for B frags
    const int rx = (g * 8) ^ ca;

    for (int s = 0; s < 32; s++) {
        // gate: slot s's 4 loads (issued in iter s-3) are the oldest of 12
        if (s <= 29)      asm volatile("s_waitcnt vmcnt(8)" ::: "memory");
        else if (s == 30) asm volatile("s_waitcnt vmcnt(4)" ::: "memory");
        else              asm volatile("s_waitcnt vmcnt(0)" ::: "memory");
        __builtin_amdgcn_sched_barrier(0);
        __builtin_amdgcn_s_barrier();            // slot s visible to ALL waves
        asm volatile("" ::: "memory");

        const int ss = (s & 3) * 8192;
        const bool st = (s < 29);
        const int s3 = (s + 3) & 3;
        const int k3 = (s + 3) * 32;
        bf16x8 bfr[4], a0, a1;

        // ---- phase 0: bfr[0..3] + af[0,1]; stage piece A-low
        bfr[0] = *(const bf16x8*)(rb + ss + 0 * 512 + rx);
        bfr[1] = *(const bf16x8*)(rb + ss + 1 * 512 + rx);
        bfr[2] = *(const bf16x8*)(rb + ss + 2 * 512 + rx);
        bfr[3] = *(const bf16x8*)(rb + ss + 3 * 512 + rx);
        a0 = *(const bf16x8*)(ra + ss + 0 * 512 + rx);
        a1 = *(const bf16x8*)(ra + ss + 1 * 512 + rx);
        if (st) gld_lds16(Ag + k3, la + s3 * 8192);
        __builtin_amdgcn_sched_barrier(0);
        __builtin_amdgcn_s_barrier();
        asm volatile("s_waitcnt lgkmcnt(0)" ::: "memory");
        __builtin_amdgcn_sched_barrier(0);
        __builtin_amdgcn_s_setprio(1);
#pragma unroll
        for (int jj = 0; jj < 4; jj++) {
            acc[0][jj] = __builtin_amdgcn_mfma_f32_16x16x32_bf16(a0, bfr[jj], acc[0][jj], 0, 0, 0);
            acc[1][jj] = __builtin_amdgcn_mfma_f32_16x16x32_bf16(a1, bfr[jj], acc[1][jj], 0, 0, 0);
        }
        __builtin_amdgcn_s_setprio(0);
        __builtin_amdgcn_sched_barrier(0);

        // ---- phase 1: af[2,3]; stage piece A-high
        a0 = *(const bf16x8*)(ra + ss + 2 * 512 + rx);
        a1 = *(const bf16x8*)(ra + ss + 3 * 512 + rx);
        if (st) gld_lds16(Ag + (size_t)128 * Kst + k3, la + s3 * 8192 + 4096);
        __builtin_amdgcn_sched_barrier(0);
        __builtin_amdgcn_s_barrier();
        asm volatile("s_waitcnt lgkmcnt(0)" ::: "memory");
        __builtin_amdgcn_sched_barrier(0);
        __builtin_amdgcn_s_setprio(1);
#pragma unroll
        for (int jj = 0; jj < 4; jj++) {
            acc[2][jj] = __builtin_amdgcn_mfma_f32_16x16x32_bf16(a0, bfr[jj], acc[2][jj], 0, 0, 0);
            acc[3][jj] = __builtin_amdgcn_mfma_f32_16x16x32_bf16(a1, bfr[jj], acc[3][jj], 0, 0, 0);
        }
        __builtin_amdgcn_s_setprio(0);
        __builtin_amdgcn_sched_barrier(0);

        // ---- phase 2: af[4,5]; stage piece B-low
        a0 = *(const bf16x8*)(ra + ss + 4 * 512 + rx);
        a1 = *(const bf16x8*)(ra + ss + 5 * 512 + rx);
        if (st) gld_lds16(Bg + k3, lb + s3 * 8192);
        __builtin_amdgcn_sched_barrier(0);
        __builtin_amdgcn_s_barrier();
        asm volatile("s_waitcnt lgkmcnt(0)" ::: "memory");
        __builtin_amdgcn_sched_barrier(0);
        __builtin_amdgcn_s_setprio(1);
#pragma unroll
        for (int jj = 0; jj < 4; jj++) {
            acc[4][jj] = __builtin_amdgcn_mfma_f32_16x16x32_bf16(a0, bfr[jj], acc[4][jj], 0, 0, 0);
            acc[5][jj] = __builtin_amdgcn_mfma_f32_16x16x32_bf16(a1, bfr[jj], acc[5][jj], 0, 0, 0);
        }
        __builtin_amdgcn_s_setprio(0);
        __builtin_amdgcn_sched_barrier(0);

        // ---- phase 3: af[6,7]; stage piece B-high
        a0 = *(const bf16x8*)(ra + ss + 6 * 512 + rx);
        a1 = *(const bf16x8*)(ra + ss + 7 * 512 + rx);
        if (st) gld_lds16(Bg + (size_t)128 * Kst + k3, lb + s3 * 8192 + 4096);
        __builtin_amdgcn_sched_barrier(0);
        __builtin_amdgcn_s_barrier();
        asm volatile("s_waitcnt lgkmcnt(0)" ::: "memory");
        __builtin_amdgcn_sched_barrier(0);
        __builtin_amdgcn_s_setprio(1);
#pragma unroll
        for (int jj = 0; jj < 4; jj++) {
            acc[6][jj] = __builtin_amdgcn_mfma_f32_16x16x32_bf16(a0, bfr[jj], acc[6][jj], 0, 0, 0);
            acc[7][jj] = __builtin_amdgcn_mfma_f32_16x16x32_bf16(a1, bfr[jj], acc[7][jj], 0, 0, 0);
        }
        __builtin_amdgcn_s_setprio(0);
        __builtin_amdgcn_sched_barrier(0);
    }
#undef G256_STAGE
}

// XCD-bijective block swizzle: ntot = NX*NY blocks (ntot % 8 == 0); each XCD
// gets a contiguous chunk of logical tiles for L2 reuse.
template<int NX>
__device__ __forceinline__ void g256_decode(int bid, int ntot, int& m0, int& n0)
{
    const int cpx = ntot >> 3;
    const int l = (bid & 7) * cpx + (bid >> 3);
    m0 = (l / NX) * 256;
    n0 = (l % NX) * 256;
}

// MODE 0: bf16 flat [M][N] (+bias, optional GELU).  MODE 4: split-K f32
// partials at [z][M][N] (blockIdx.z = K-slice of 1024).
template<int MODE, int ACT, int NX>
__global__ __launch_bounds__(512, 1) void g256(
    const __bf16* __restrict__ A, const __bf16* __restrict__ Bt,
    const float* __restrict__ bias, void* __restrict__ outp,
    int M, int N, int Kst)
{
    __shared__ __bf16 SA[4][256][32];
    __shared__ __bf16 SB[4][256][32];
    int m0, n0;
    g256_decode<NX>(blockIdx.x, NX * (M >> 8), m0, n0);
    const int kbeg = (MODE == 4) ? (blockIdx.z << 10) : 0;

    floatx4 acc[8][4] = {};
    g256_loop(A, Bt, Kst, kbeg, m0, n0, &SA[0][0][0], &SB[0][0][0], acc);

    const int tid = threadIdx.x, lane = tid & 63, wave = tid >> 6;
    const int g = lane >> 4, c = lane & 15;
    const int wm = wave >> 2, wn = wave & 3;

    __bf16* obf = (__bf16*)outp;
    float*  of  = (float*)outp;
#pragma unroll
    for (int i = 0; i < 8; i++) {
#pragma unroll
        for (int jj = 0; jj < 4; jj++) {
            const int row = m0 + wm * 128 + i * 16 + g * 4;
            const int col = n0 + wn * 64 + jj * 16 + c;
            const float bb = (MODE == 4) ? 0.0f : bias[col];
            float xs[4];
#pragma unroll
            for (int rr = 0; rr < 4; rr++) {
                float x = acc[i][jj][rr] + bb;
                if (ACT == 1) x = gelu_fast(x);
                xs[rr] = x;
            }
            if (MODE == 0) {
#pragma unroll
                for (int rr = 0; rr < 4; rr++)
                    obf[(size_t)(row + rr) * N + col] = (__bf16)xs[rr];
            } else if (MODE == 4) {
#pragma unroll
                for (int rr = 0; rr < 4; rr++)
                    of[((size_t)blockIdx.z * M + row + rr) * N + col] = xs[rr];
            }
        }
    }
}

// Fused Q/K/V projection on the 256-tile core.  grid (64,1,3).
__global__ __launch_bounds__(512, 1) void g256qkv(
    const __bf16* __restrict__ Xn, const __bf16* __restrict__ Yn,
    const __bf16* __restrict__ WqT, const __bf16* __restrict__ WkT,
    const __bf16* __restrict__ WvT,
    const float* __restrict__ bq, const float* __restrict__ bk,
    const float* __restrict__ bv,
    __bf16* __restrict__ Qbf, __bf16* __restrict__ Kbf,
    __bf16* __restrict__ Vt)
{
    __shared__ __bf16 SA[4][256][32];
    __shared__ __bf16 SB[4][256][32];
    const int z = blockIdx.z;
    const __bf16* A    = (z == 0) ? Xn  : Yn;
    const __bf16* Bt   = (z == 0) ? WqT : (z == 1) ? WkT : WvT;
    const float*  bias = (z == 0) ? bq  : (z == 1) ? bk  : bv;

    int m0, n0;
    g256_decode<4>(blockIdx.x, 64, m0, n0);

    floatx4 acc[8][4] = {};
    g256_loop(A, Bt, DM, 0, m0, n0, &SA[0][0][0], &SB[0][0][0], acc);

    const int tid = threadIdx.x, lane = tid & 63, wave = tid >> 6;
    const int g = lane >> 4, c = lane & 15;
    const int wm = wave >> 2, wn = wave & 3;

#pragma unroll
    for (int i = 0; i < 8; i++) {
#pragma unroll
        for (int jj = 0; jj < 4; jj++) {
            const int row = m0 + wm * 128 + i * 16 + g * 4;
            const int col = n0 + wn * 64 + jj * 16 + c;
            const float bb = bias[col];
            float xs[4];
#pragma unroll
            for (int rr = 0; rr < 4; rr++) xs[rr] = acc[i][jj][rr] + bb;
            if (z == 0) {
#pragma unroll
                for (int rr = 0; rr < 4; rr++)
                    Qbf[(size_t)(row + rr) * DM + col] = (__bf16)xs[rr];
            } else if (z == 1) {
#pragma unroll
                for (int rr = 0; rr < 4; rr++) {
                    const int r2 = row + rr;
                    Kbf[(size_t)(r2 + (r2 >> 11)) * DM + col] = (__bf16)xs[rr];
                }
            } else {
                const int b  = row >> 11;
                const int kv = row & 2047;
                const size_t base =
                    ((size_t)((b * NH + (col >> 6)) * DHD + (col & 63))) * 2056 + kv;
                bf16x4 pk;
                pk[0] = (__bf16)xs[0]; pk[1] = (__bf16)xs[1];
                pk[2] = (__bf16)xs[2]; pk[3] = (__bf16)xs[3];
                *(bf16x4*)(Vt + base) = pk;
            }
        }
    }
}

// ---------------------------------------------------------------------------
// FF2 split-K reduction: out = sum_z partials[z] + bias + Hres.  float4/thread.
// ---------------------------------------------------------------------------
__global__ __launch_bounds__(256) void ff2_reduce(
    const float* __restrict__ part, const float* __restrict__ bias,
    const float* __restrict__ Hres, float* __restrict__ out)
{
    const size_t f4 = (size_t)blockIdx.x * 256 + threadIdx.x;  // float4 index
    const int c4 = (int)(f4 & (DM / 4 - 1));
    const size_t stride4 = (size_t)ROWS * DM / 4;
    float4 a = ((const float4*)part)[f4];
    const float4 p1 = ((const float4*)part)[f4 + stride4];
    const float4 p2 = ((const float4*)part)[f4 + 2 * stride4];
    const float4 p3 = ((const float4*)part)[f4 + 3 * stride4];
    const float4 b  = ((const float4*)bias)[c4];
    const float4 hr = ((const float4*)Hres)[f4];
    a.x += p1.x + p2.x + p3.x + b.x + hr.x;
    a.y += p1.y + p2.y + p3.y + b.y + hr.y;
    a.z += p1.z + p2.z + p3.z + b.z + hr.z;
    a.w += p1.w + p2.w + p3.w + b.w + hr.w;
    ((float4*)out)[f4] = a;
}

// ---------------------------------------------------------------------------
// Flash attention (round-6 proven): 128 q/block, 32 q/wave; gld_lds
// XOR-swizzled staging; 4-slot ring, 2 tiles per barrier; v_perm pack;
// ones-MFMA denominator; XCD-local heads.
// ---------------------------------------------------------------------------
__global__ __launch_bounds__(256, 2) void attn_kernel(
    const __bf16* __restrict__ Q, const __bf16* __restrict__ Kb,
    const __bf16* __restrict__ Vt, __bf16* __restrict__ O)
{
    __shared__ __bf16 Ks[4][64][64];   // [kv][d]   32 KB
    __shared__ __bf16 Vs[4][64][64];   // [d][kv]   32 KB

    const int tid = threadIdx.x, lane = tid & 63, w = tid >> 6;
    const int g = lane >> 4, c = lane & 15;

    const int hw   = blockIdx.x;
    const int slot = hw >> 3;
    const int hb   = (hw & 7) | ((slot >> 4) << 3);   // 0..31
    const int h = hb & 15, b = hb >> 4;
    const int q0w = (slot & 15) * 128 + w * 32;

    const float QSC = 0.03125f * 1.44269504088896f;
    bf16x8 qf[2][2];
#pragma unroll
    for (int qt = 0; qt < 2; qt++) {
        const __bf16* Qbase = Q + ((size_t)(b * NQS + q0w + qt * 16 + c)) * DM + h * DHD;
        qf[qt][0] = *(const bf16x8*)(Qbase + g * 8);
        qf[qt][1] = *(const bf16x8*)(Qbase + 32 + g * 8);
#pragma unroll
        for (int e = 0; e < 8; e++) {
            qf[qt][0][e] = (__bf16)((float)qf[qt][0][e] * QSC);
            qf[qt][1][e] = (__bf16)((float)qf[qt][1][e] * QSC);
        }
    }

    // ones fragment for the denominator MFMA (bf16 1.0 = 0x3F80)
    shortx4 ones;
    ones[0] = ones[1] = ones[2] = ones[3] = (short)0x3F80;

    floatx4 dacc[2] = {};        // denominator accumulators (rows identical)
    floatx4 oacc[2][4] = {};

    const int srow = tid >> 3;                    // LDS row 0..31 (and +32)
    const int schk = (tid & 7) ^ (srow & 7);      // swizzled 16B source chunk
    const __bf16* Kg  = Kb + (size_t)b * NKV1 * DM + h * DHD + schk * 8;
    const __bf16* Vg  = Vt + ((size_t)(b * NH + h) * DHD + srow) * 2056;
    const __bf16* Vg2 = Vg + (size_t)32 * 2056;
    const int vcol0 = schk * 8;

    auto stage = [&](int p, int kv0, bool tail) {
        __bf16* kd0 = &Ks[p][0][0]  + tid * 8;
        __bf16* kd1 = &Ks[p][32][0] + tid * 8;
        __bf16* vd0 = &Vs[p][0][0]  + tid * 8;
        __bf16* vd1 = &Vs[p][32][0] + tid * 8;
        if (!tail) {
            gld_lds16(Kg + (size_t)(kv0 + srow) * DM, kd0);
            gld_lds16(Kg + (size_t)(kv0 + srow + 32) * DM, kd1);
            gld_lds16(Vg + kv0 + vcol0, vd0);
            gld_lds16(Vg2 + kv0 + vcol0, vd1);
        } else {
            const int r0 = min(kv0 + srow, NKVS);
            const int r1 = min(kv0 + srow + 32, NKVS);
            const int vc = min(kv0 + vcol0, NKVS);
            gld_lds16(Kg + (size_t)r0 * DM, kd0);
            gld_lds16(Kg + (size_t)r1 * DM, kd1);
            gld_lds16(Vg + vc, vd0);
            gld_lds16(Vg2 + vc, vd1);
        }
    };

    auto compute = [&](int p, int kv0, bool tail) {
        floatx4 s[2][4];
#pragma unroll
        for (int qt = 0; qt < 2; qt++)
#pragma unroll
            for (int kvt = 0; kvt < 4; kvt++)
#pragma unroll
                for (int r = 0; r < 4; r++) s[qt][kvt][r] = -6.0f;

        const int sw = c & 7;
        __builtin_amdgcn_s_setprio(1);
#pragma unroll
        for (int kvt = 0; kvt < 4; kvt++) {
            const bf16x8 kf0 = *(const bf16x8*)&Ks[p][kvt * 16 + c][(g ^ sw) * 8];
            const bf16x8 kf1 = *(const bf16x8*)&Ks[p][kvt * 16 + c][((4 | g) ^ sw) * 8];
#pragma unroll
            for (int qt = 0; qt < 2; qt++) {
                s[qt][kvt] = __builtin_amdgcn_mfma_f32_16x16x32_bf16(kf0, qf[qt][0], s[qt][kvt], 0, 0, 0);
                s[qt][kvt] = __builtin_amdgcn_mfma_f32_16x16x32_bf16(kf1, qf[qt][1], s[qt][kvt], 0, 0, 0);
            }
        }
        __builtin_amdgcn_s_setprio(0);

        if (tail) {
#pragma unroll
            for (int qt = 0; qt < 2; qt++)
#pragma unroll
                for (int kvt = 0; kvt < 4; kvt++)
#pragma unroll
                    for (int r = 0; r < 4; r++)
                        if (kv0 + kvt * 16 + g * 4 + r >= NKV1) s[qt][kvt][r] = -1e30f;
        }

        // p = exp2(s); pack to bf16 by truncation via v_perm (1 op per word)
        shortx4 pf[2][4];
#pragma unroll
        for (int qt = 0; qt < 2; qt++)
#pragma unroll
            for (int kvt = 0; kvt < 4; kvt++) {
                const unsigned u0 = __builtin_bit_cast(unsigned, __builtin_amdgcn_exp2f(s[qt][kvt][0]));
                const unsigned u1 = __builtin_bit_cast(unsigned, __builtin_amdgcn_exp2f(s[qt][kvt][1]));
                const unsigned u2 = __builtin_bit_cast(unsigned, __builtin_amdgcn_exp2f(s[qt][kvt][2]));
                const unsigned u3 = __builtin_bit_cast(unsigned, __builtin_amdgcn_exp2f(s[qt][kvt][3]));
                unsigned pk0 = __builtin_amdgcn_perm(u1, u0, 0x07060302u);
                unsigned pk1 = __builtin_amdgcn_perm(u3, u2, 0x07060302u);
                unsigned long long pk = ((unsigned long long)pk1 << 32) | pk0;
                pf[qt][kvt] = __builtin_bit_cast(shortx4, pk);
            }

        // O^T += V^T P^T ; denominator via ones-row MFMA
        __builtin_amdgcn_s_setprio(1);
#pragma unroll
        for (int kvt = 0; kvt < 4; kvt++) {
            shortx4 vfr[4];
#pragma unroll
            for (int dt = 0; dt < 4; dt++) {
                const int slotp = (kvt * 2 + (g >> 1)) ^ sw;
                vfr[dt] = *(const shortx4*)&Vs[p][dt * 16 + c][slotp * 8 + (g & 1) * 4];
            }
#pragma unroll
            for (int dt = 0; dt < 4; dt++)
#pragma unroll
                for (int qt = 0; qt < 2; qt++)
                    oacc[qt][dt] = __builtin_amdgcn_mfma_f32_16x16x16bf16_1k(
                        vfr[dt], pf[qt][kvt], oacc[qt][dt], 0, 0, 0);
#pragma unroll
            for (int qt = 0; qt < 2; qt++)
                dacc[qt] = __builtin_amdgcn_mfma_f32_16x16x16bf16_1k(
                    ones, pf[qt][kvt], dacc[qt], 0, 0, 0);
        }
        __builtin_amdgcn_s_setprio(0);
    };

    // 4-slot ring, 2 tiles per barrier period.  Tiles 0..32 (32 = tail).
    stage(0, 0, false);
    stage(1, 64, false);
    __syncthreads();
    for (int it = 0; it < 32; it += 2) {
        stage((it + 2) & 3, (it + 2) * 64, (it + 2) == 32);
        if (it + 3 <= 32) stage((it + 3) & 3, (it + 3) * 64, false);
        compute(it & 3, it * 64, false);
        compute((it + 1) & 3, (it + 1) * 64, false);
        __syncthreads();                 // staged tiles visible; reads done
    }
    compute(0, 2048, true);              // tail tile (32) in slot 0

#pragma unroll
    for (int qt = 0; qt < 2; qt++) {
        const float inv_l = 1.0f / dacc[qt][0];
        __bf16* Ob = O + ((size_t)(b * NQS + q0w + qt * 16 + c)) * DM + h * DHD;
#pragma unroll
        for (int dt = 0; dt < 4; dt++) {
            bf16x4 ob;
#pragma unroll
            for (int r = 0; r < 4; r++) ob[r] = (__bf16)(oacc[qt][dt][r] * inv_l);
            *(bf16x4*)(Ob + dt * 16 + g * 4) = ob;
        }
    }
}

// ---------------------------------------------------------------------------
extern "C" void kernel_launch(void* const* d_in, const int* in_sizes, int n_in,
                              void* d_out, int out_size, void* d_ws, size_t ws_size,
                              hipStream_t stream)
{
    const float* X      = (const float*)d_in[0];
    const float* Y      = (const float*)d_in[1];
    const float* Wq     = (const float*)d_in[2];
    const float* bq     = (const float*)d_in[3];
    const float* Wk     = (const float*)d_in[4];
    const float* bk     = (const float*)d_in[5];
    const float* Wv     = (const float*)d_in[6];
    const float* bv     = (const float*)d_in[7];
    const float* null_k = (const float*)d_in[8];
    const float* g0     = (const float*)d_in[9];
    const float* b0     = (const float*)d_in[10];
    const float* g0kv   = (const float*)d_in[11];
    const float* b0kv   = (const float*)d_in[12];
    const float* g1     = (const float*)d_in[13];
    const float* b1     = (const float*)d_in[14];
    const float* W1     = (const float*)d_in[15];
    const float* bf1    = (const float*)d_in[16];
    const float* W2     = (const float*)d_in[17];
    const float* bf2    = (const float*)d_in[18];
    float* out = (float*)d_out;

    // workspace carve (bytes).  Persistent-through-FF2 buffers FIRST so the
    // tail region (dead by FF2 time) can be reused for split-K partials.
    char* p = (char*)d_ws;
    __bf16* W2T  = (__bf16*)p; p += (size_t)4 * DM * DM * 2;          // [1024][4096]
    float*  Hres = (float*)p;  p += (size_t)ROWS * DM * 4;
    __bf16* Gbf  = (__bf16*)p; p += (size_t)ROWS * 4 * DM * 2;
    char* scratch = p;                                                // dead by FF2
    __bf16* Xn   = (__bf16*)p; p += (size_t)ROWS * DM * 2;
    __bf16* Yn   = (__bf16*)p; p += (size_t)ROWS * DM * 2;
    __bf16* WqT  = (__bf16*)p; p += (size_t)DM * DM * 2;
    __bf16* WkT  = (__bf16*)p; p += (size_t)DM * DM * 2;
    __bf16* WvT  = (__bf16*)p; p += (size_t)DM * DM * 2;
    __bf16* W1T  = (__bf16*)p; p += (size_t)4 * DM * DM * 2;          // [4096][1024]
    __bf16* Qbf  = (__bf16*)p; p += (size_t)ROWS * DM * 2;
    __bf16* Kbf  = (__bf16*)p; p += (size_t)BATCH * NKV1 * DM * 2;
    __bf16* Vt   = (__bf16*)p; p += (size_t)BATCH * NH * DHD * 2056 * 2;
    __bf16* Obf  = (__bf16*)p; p += (size_t)ROWS * DM * 2;
    __bf16* Hr   = (__bf16*)p; p += (size_t)ROWS * DM * 2;
    float* Part  = (float*)scratch;  // FF2 partials: 4 x ROWS x DM f32 = 67 MB

    // 1. LayerNorms (fused X+Y, one launch)
    ln2_to_bf16<<<2 * ROWS, 256, 0, stream>>>(X, Y, g0, b0, g0kv, b0kv, Xn, Yn);

    // 2. weight transposes (f32 -> bf16, W^T), two launches total
    transpose3_f32_bf16<<<dim3(DM / 32, DM / 32, 3), dim3(32, 8), 0, stream>>>(
        Wq, Wk, Wv, WqT, WkT, WvT);
    transpose_ffw<<<dim3(128, 32, 2), dim3(32, 8), 0, stream>>>(W1, W2, W1T, W2T);

    // 3. fused Q/K/V projections on the 8-phase 256-tile core
    g256qkv<<<dim3(64, 1, 3), 512, 0, stream>>>(
        Xn, Yn, WqT, WkT, WvT, bq, bk, bv, Qbf, Kbf, Vt);
    fill_null<<<64, 256, 0, stream>>>(null_k, Kbf, Vt);

    // 4. attention (4-slot ring, 2 tiles/barrier, XCD-local heads)
    attn_kernel<<<dim3(512), 256, 0, stream>>>(Qbf, Kbf, Vt, Obf);

    // 5. residual + LN
    resid_ln<<<ROWS, 256, 0, stream>>>(X, Obf, g1, b1, Hres, Hr);

    // 6. FFN: FF1 (bf16 + GELU), FF2 split-K=4 partials, then reduce
    g256<0, 1, 16><<<dim3(256), 512, 0, stream>>>(
        Hr, W1T, bf1, (void*)Gbf, ROWS, 4 * DM, DM);
    g256<4, 0, 4><<<dim3(64, 1, 4), 512, 0, stream>>>(
        Gbf, W2T, bf2, (void*)Part, ROWS, DM, 4 * DM);
    ff2_reduce<<<ROWS * DM / 1024, 256, 0, stream>>>(Part, bf2, Hres, out);
}

// Round 8
// 341.333 us; speedup vs baseline: 1.1029x; 1.0020x over previous
//
#include <hip/hip_runtime.h>
#include <hip/hip_bf16.h>
#include <math.h>
#include <stdint.h>

typedef __bf16 bf16x8 __attribute__((ext_vector_type(8)));
typedef __bf16 bf16x4 __attribute__((ext_vector_type(4)));
typedef float floatx4 __attribute__((ext_vector_type(4)));
typedef short shortx4 __attribute__((ext_vector_type(4)));

#define NQS   2048
#define NKVS  2048
#define NKV1  2049
#define DM    1024
#define NH    16
#define DHD   64
#define BATCH 2
#define ROWS  (BATCH * NQS)   // 4096

// async global->LDS, 16B per lane. LDS dest must be wave-uniform base + lane*16.
__device__ __forceinline__ void gld_lds16(const __bf16* gp, __bf16* lp) {
    __builtin_amdgcn_global_load_lds(
        (const __attribute__((address_space(1))) uint32_t*)(uintptr_t)gp,
        (__attribute__((address_space(3))) uint32_t*)(uintptr_t)lp,
        16, 0, 0);
}

// tanh-form GELU in exp2 domain
__device__ __forceinline__ float gelu_fast(float x) {
    const float u = x * x;
    const float e = __builtin_amdgcn_exp2f(x * (-2.3022077f + (-0.1029431f) * u));
    return x * __builtin_amdgcn_rcpf(1.0f + e);
}

// ---------------------------------------------------------------------------
// Fused LayerNorm for X and Y (f32 in) -> bf16 out.  grid 2*ROWS.
// ---------------------------------------------------------------------------
__global__ __launch_bounds__(256) void ln2_to_bf16(
    const float* __restrict__ X, const float* __restrict__ Y,
    const float* __restrict__ g0, const float* __restrict__ b0,
    const float* __restrict__ g0kv, const float* __restrict__ b0kv,
    __bf16* __restrict__ Xn, __bf16* __restrict__ Yn)
{
    int row = blockIdx.x;
    const float *src, *gamma, *beta; __bf16* dst;
    if (row < ROWS) { src = X; gamma = g0; beta = b0; dst = Xn; }
    else { row -= ROWS; src = Y; gamma = g0kv; beta = b0kv; dst = Yn; }
    const int tid = threadIdx.x;
    const float4 v = ((const float4*)(src + (size_t)row * DM))[tid];
    float s  = v.x + v.y + v.z + v.w;
    float sq = v.x * v.x + v.y * v.y + v.z * v.z + v.w * v.w;
    for (int off = 1; off < 64; off <<= 1) {
        s  += __shfl_xor(s, off);
        sq += __shfl_xor(sq, off);
    }
    __shared__ float red[8];
    const int wave = tid >> 6, lane = tid & 63;
    if (lane == 0) { red[wave * 2] = s; red[wave * 2 + 1] = sq; }
    __syncthreads();
    s  = red[0] + red[2] + red[4] + red[6];
    sq = red[1] + red[3] + red[5] + red[7];
    const float mu  = s * (1.0f / DM);
    const float var = sq * (1.0f / DM) - mu * mu;
    const float rs  = rsqrtf(var + 1e-5f);
    const float4 gv = ((const float4*)gamma)[tid];
    const float4 bv = ((const float4*)beta)[tid];
    bf16x4 o;
    o[0] = (__bf16)((v.x - mu) * rs * gv.x + bv.x);
    o[1] = (__bf16)((v.y - mu) * rs * gv.y + bv.y);
    o[2] = (__bf16)((v.z - mu) * rs * gv.z + bv.z);
    o[3] = (__bf16)((v.w - mu) * rs * gv.w + bv.w);
    *(bf16x4*)(dst + (size_t)row * DM + tid * 4) = o;
}

// ---------------------------------------------------------------------------
// Residual add + LayerNorm: Hres = X + O (f32 out), Hr = LN(Hres) (bf16 out)
// ---------------------------------------------------------------------------
__global__ __launch_bounds__(256) void resid_ln(
    const float* __restrict__ X, const __bf16* __restrict__ O,
    const float* __restrict__ gamma, const float* __restrict__ beta,
    float* __restrict__ Hres, __bf16* __restrict__ Hr)
{
    const int row = blockIdx.x;
    const int tid = threadIdx.x;
    const float4 xv = ((const float4*)(X + (size_t)row * DM))[tid];
    const bf16x4 ov = *(const bf16x4*)(O + (size_t)row * DM + tid * 4);
    float4 v;
    v.x = xv.x + (float)ov[0];
    v.y = xv.y + (float)ov[1];
    v.z = xv.z + (float)ov[2];
    v.w = xv.w + (float)ov[3];
    ((float4*)(Hres + (size_t)row * DM))[tid] = v;

    float s  = v.x + v.y + v.z + v.w;
    float sq = v.x * v.x + v.y * v.y + v.z * v.z + v.w * v.w;
    for (int off = 1; off < 64; off <<= 1) {
        s  += __shfl_xor(s, off);
        sq += __shfl_xor(sq, off);
    }
    __shared__ float red[8];
    const int wave = tid >> 6, lane = tid & 63;
    if (lane == 0) { red[wave * 2] = s; red[wave * 2 + 1] = sq; }
    __syncthreads();
    s  = red[0] + red[2] + red[4] + red[6];
    sq = red[1] + red[3] + red[5] + red[7];
    const float mu  = s * (1.0f / DM);
    const float var = sq * (1.0f / DM) - mu * mu;
    const float rs  = rsqrtf(var + 1e-5f);
    const float4 gv = ((const float4*)gamma)[tid];
    const float4 bv = ((const float4*)beta)[tid];
    bf16x4 o;
    o[0] = (__bf16)((v.x - mu) * rs * gv.x + bv.x);
    o[1] = (__bf16)((v.y - mu) * rs * gv.y + bv.y);
    o[2] = (__bf16)((v.z - mu) * rs * gv.z + bv.z);
    o[3] = (__bf16)((v.w - mu) * rs * gv.w + bv.w);
    *(bf16x4*)(Hr + (size_t)row * DM + tid * 4) = o;
}

// Fused transpose of the three 1024x1024 QKV weights (one launch, z picks W).
__global__ __launch_bounds__(256) void transpose3_f32_bf16(
    const float* __restrict__ Wq, const float* __restrict__ Wk,
    const float* __restrict__ Wv, __bf16* __restrict__ WqT,
    __bf16* __restrict__ WkT, __bf16* __restrict__ WvT)
{
    __shared__ float tile[32][33];
    const int z = blockIdx.z;
    const float* in = (z == 0) ? Wq : (z == 1) ? Wk : Wv;
    __bf16* out = (z == 0) ? WqT : (z == 1) ? WkT : WvT;
    const int c0 = blockIdx.x * 32, r0 = blockIdx.y * 32;
    const int tx = threadIdx.x, ty = threadIdx.y;
#pragma unroll
    for (int i = 0; i < 4; i++)
        tile[ty + i * 8][tx] = in[(size_t)(r0 + ty + i * 8) * DM + c0 + tx];
    __syncthreads();
#pragma unroll
    for (int i = 0; i < 4; i++)
        out[(size_t)(c0 + ty + i * 8) * DM + r0 + tx] = (__bf16)tile[tx][ty + i * 8];
}

// Fused transpose of W1 [1024][4096] and W2 [4096][1024] (z picks).
__global__ __launch_bounds__(256) void transpose_ffw(
    const float* __restrict__ W1, const float* __restrict__ W2,
    __bf16* __restrict__ W1T, __bf16* __restrict__ W2T)
{
    __shared__ float tile[32][33];
    const int z = blockIdx.z;
    const float* in; __bf16* out; int R, C, c0, r0;
    if (z == 0) { in = W1; out = W1T; R = DM; C = 4 * DM; c0 = blockIdx.x * 32; r0 = blockIdx.y * 32; }
    else        { in = W2; out = W2T; R = 4 * DM; C = DM; c0 = blockIdx.y * 32; r0 = blockIdx.x * 32; }
    const int tx = threadIdx.x, ty = threadIdx.y;
#pragma unroll
    for (int i = 0; i < 4; i++)
        tile[ty + i * 8][tx] = in[(size_t)(r0 + ty + i * 8) * C + c0 + tx];
    __syncthreads();
#pragma unroll
    for (int i = 0; i < 4; i++)
        out[(size_t)(c0 + ty + i * 8) * R + r0 + tx] = (__bf16)tile[tx][ty + i * 8];
}

// ---------------------------------------------------------------------------
// Fill null-K row (kv==2048) with null_k, and zero Vt pad columns [2048,2056)
// ---------------------------------------------------------------------------
__global__ __launch_bounds__(256) void fill_null(
    const float* __restrict__ null_k, __bf16* __restrict__ Kb,
    __bf16* __restrict__ Vt)
{
    const int i = blockIdx.x * 256 + threadIdx.x;
    if (i < BATCH * DM) {
        const int b = i >> 10, d = i & (DM - 1);
        Kb[((size_t)b * NKV1 + NKVS) * DM + d] = (__bf16)null_k[d];
    }
    if (i < BATCH * NH * DHD * 8) {  // 16384
        const int bhd = i >> 3, kvp = i & 7;
        Vt[(size_t)bhd * 2056 + 2048 + kvp] = (__bf16)0.0f;
    }
}

// ---------------------------------------------------------------------------
// 256x256-tile GEMM core, 2-phase x 16-MFMA schedule:
// 512 threads (8 waves, 2Mx4N), per-wave 128x64 output.  K as 32 subtiles of
// BK=32 in a 4-slot LDS ring (128 KiB), global_load_lds, 3 subtiles ahead,
// counted vmcnt(8/4/0).  Per subtile: ONE top barrier (slot visibility +
// WAR gate for staging into slot s-1), then
//   phase A: 8 ds_read (bfr[0..3], af rows 0..3) ; 2 gld_lds (A of s+3) ;
//            setprio(1) 16 MFMA acc[0..3]
//   mid s_barrier (wave alignment)
//   phase B: 4 ds_read (af rows 4..7) ; 2 gld_lds (B of s+3) ;
//            setprio(1) 16 MFMA acc[4..7]
// ds_read->MFMA waits left to the compiler (fine-grained lgkmcnt);
// sched_barrier(0) pins the read/stage vs MFMA boundary.
// LDS source pre-swizzled: phys chunk j of row r holds logical j^(r&3).
// ---------------------------------------------------------------------------
__device__ __forceinline__ void g256_loop(
    const __bf16* __restrict__ A, const __bf16* __restrict__ Bt,
    int Kst, int kbeg, int m0, int n0,
    __bf16* sa, __bf16* sb, floatx4 (&acc)[8][4])
{
    const int tid = threadIdx.x, lane = tid & 63;
    const int g = lane >> 4, c = lane & 15;
    const int wave = tid >> 6;
    const int wm = wave >> 2, wn = wave & 3;

    const int r = tid >> 2, j = tid & 3;
    const int jx = (j ^ (r & 3)) * 8;            // swizzled source chunk (elems)
    const __bf16* Ag = A  + (size_t)(m0 + r) * Kst + kbeg + jx;
    const __bf16* Bg = Bt + (size_t)(n0 + r) * Kst + kbeg + jx;
    __bf16* la = sa + tid * 8;                   // byte offset tid*16
    __bf16* lb = sb + tid * 8;

#define G256_STAGE(ss, koff) do {                                          \
    gld_lds16(Ag + (koff),                      la + (ss) * 8192);         \
    gld_lds16(Ag + (size_t)128 * Kst + (koff),  la + (ss) * 8192 + 4096);  \
    gld_lds16(Bg + (koff),                      lb + (ss) * 8192);         \
    gld_lds16(Bg + (size_t)128 * Kst + (koff),  lb + (ss) * 8192 + 4096);  \
} while (0)

    // prologue: 3 subtiles in flight
    G256_STAGE(0, 0);
    G256_STAGE(1, 32);
    G256_STAGE(2, 64);

    const int ca = (c & 3) * 8;                  // read-side XOR (elems)
    const __bf16* ra = sa + (wm * 128 + c) * 32; // row base for A frags
    const __bf16* rb = sb + (wn * 64 + c) * 32;  // row base for B frags
    const int rx = (g * 8) ^ ca;

    for (int s = 0; s < 32; s++) {
        // gate: slot s's 4 loads (issued in iter s-3) are the oldest of 12
        if (s <= 29)      asm volatile("s_waitcnt vmcnt(8)" ::: "memory");
        else if (s == 30) asm volatile("s_waitcnt vmcnt(4)" ::: "memory");
        else              asm volatile("s_waitcnt vmcnt(0)" ::: "memory");
        __builtin_amdgcn_sched_barrier(0);
        __builtin_amdgcn_s_barrier();            // slot s visible; iter s-1
        asm volatile("" ::: "memory");           // reads retired (WAR-safe)

        const int ss = (s & 3) * 8192;
        const bool st = (s < 29);
        const int s3 = (s + 3) & 3;
        const int k3 = (s + 3) * 32;
        bf16x8 bfr[4], a0, a1, a2, a3;

        // ---- phase A: B frags + A rows 0..3; stage A-halves of s+3
        bfr[0] = *(const bf16x8*)(rb + ss + 0 * 512 + rx);
        bfr[1] = *(const bf16x8*)(rb + ss + 1 * 512 + rx);
        bfr[2] = *(const bf16x8*)(rb + ss + 2 * 512 + rx);
        bfr[3] = *(const bf16x8*)(rb + ss + 3 * 512 + rx);
        a0 = *(const bf16x8*)(ra + ss + 0 * 512 + rx);
        a1 = *(const bf16x8*)(ra + ss + 1 * 512 + rx);
        a2 = *(const bf16x8*)(ra + ss + 2 * 512 + rx);
        a3 = *(const bf16x8*)(ra + ss + 3 * 512 + rx);
        if (st) {
            gld_lds16(Ag + k3, la + s3 * 8192);
            gld_lds16(Ag + (size_t)128 * Kst + k3, la + s3 * 8192 + 4096);
        }
        __builtin_amdgcn_sched_barrier(0);
        __builtin_amdgcn_s_setprio(1);
#pragma unroll
        for (int jj = 0; jj < 4; jj++) {
            acc[0][jj] = __builtin_amdgcn_mfma_f32_16x16x32_bf16(a0, bfr[jj], acc[0][jj], 0, 0, 0);
            acc[1][jj] = __builtin_amdgcn_mfma_f32_16x16x32_bf16(a1, bfr[jj], acc[1][jj], 0, 0, 0);
            acc[2][jj] = __builtin_amdgcn_mfma_f32_16x16x32_bf16(a2, bfr[jj], acc[2][jj], 0, 0, 0);
            acc[3][jj] = __builtin_amdgcn_mfma_f32_16x16x32_bf16(a3, bfr[jj], acc[3][jj], 0, 0, 0);
        }
        __builtin_amdgcn_s_setprio(0);
        __builtin_amdgcn_sched_barrier(0);
        __builtin_amdgcn_s_barrier();            // mid-phase wave alignment
        asm volatile("" ::: "memory");

        // ---- phase B: A rows 4..7; stage B-halves of s+3
        a0 = *(const bf16x8*)(ra + ss + 4 * 512 + rx);
        a1 = *(const bf16x8*)(ra + ss + 5 * 512 + rx);
        a2 = *(const bf16x8*)(ra + ss + 6 * 512 + rx);
        a3 = *(const bf16x8*)(ra + ss + 7 * 512 + rx);
        if (st) {
            gld_lds16(Bg + k3, lb + s3 * 8192);
            gld_lds16(Bg + (size_t)128 * Kst + k3, lb + s3 * 8192 + 4096);
        }
        __builtin_amdgcn_sched_barrier(0);
        __builtin_amdgcn_s_setprio(1);
#pragma unroll
        for (int jj = 0; jj < 4; jj++) {
            acc[4][jj] = __builtin_amdgcn_mfma_f32_16x16x32_bf16(a0, bfr[jj], acc[4][jj], 0, 0, 0);
            acc[5][jj] = __builtin_amdgcn_mfma_f32_16x16x32_bf16(a1, bfr[jj], acc[5][jj], 0, 0, 0);
            acc[6][jj] = __builtin_amdgcn_mfma_f32_16x16x32_bf16(a2, bfr[jj], acc[6][jj], 0, 0, 0);
            acc[7][jj] = __builtin_amdgcn_mfma_f32_16x16x32_bf16(a3, bfr[jj], acc[7][jj], 0, 0, 0);
        }
        __builtin_amdgcn_s_setprio(0);
        __builtin_amdgcn_sched_barrier(0);
    }
#undef G256_STAGE
}

// XCD-bijective block swizzle: ntot = NX*NY blocks (ntot % 8 == 0); each XCD
// gets a contiguous chunk of logical tiles for L2 reuse.
template<int NX>
__device__ __forceinline__ void g256_decode(int bid, int ntot, int& m0, int& n0)
{
    const int cpx = ntot >> 3;
    const int l = (bid & 7) * cpx + (bid >> 3);
    m0 = (l / NX) * 256;
    n0 = (l % NX) * 256;
}

// MODE 0: bf16 flat [M][N] (+bias, optional GELU).  MODE 4: split-K f32
// partials at [z][M][N] (blockIdx.z = K-slice of 1024).
template<int MODE, int ACT, int NX>
__global__ __launch_bounds__(512, 1) void g256(
    const __bf16* __restrict__ A, const __bf16* __restrict__ Bt,
    const float* __restrict__ bias, void* __restrict__ outp,
    int M, int N, int Kst)
{
    __shared__ __bf16 SA[4][256][32];
    __shared__ __bf16 SB[4][256][32];
    int m0, n0;
    g256_decode<NX>(blockIdx.x, NX * (M >> 8), m0, n0);
    const int kbeg = (MODE == 4) ? (blockIdx.z << 10) : 0;

    floatx4 acc[8][4] = {};
    g256_loop(A, Bt, Kst, kbeg, m0, n0, &SA[0][0][0], &SB[0][0][0], acc);

    const int tid = threadIdx.x, lane = tid & 63, wave = tid >> 6;
    const int g = lane >> 4, c = lane & 15;
    const int wm = wave >> 2, wn = wave & 3;

    __bf16* obf = (__bf16*)outp;
    float*  of  = (float*)outp;
#pragma unroll
    for (int i = 0; i < 8; i++) {
#pragma unroll
        for (int jj = 0; jj < 4; jj++) {
            const int row = m0 + wm * 128 + i * 16 + g * 4;
            const int col = n0 + wn * 64 + jj * 16 + c;
            const float bb = (MODE == 4) ? 0.0f : bias[col];
            float xs[4];
#pragma unroll
            for (int rr = 0; rr < 4; rr++) {
                float x = acc[i][jj][rr] + bb;
                if (ACT == 1) x = gelu_fast(x);
                xs[rr] = x;
            }
            if (MODE == 0) {
#pragma unroll
                for (int rr = 0; rr < 4; rr++)
                    obf[(size_t)(row + rr) * N + col] = (__bf16)xs[rr];
            } else if (MODE == 4) {
#pragma unroll
                for (int rr = 0; rr < 4; rr++)
                    of[((size_t)blockIdx.z * M + row + rr) * N + col] = xs[rr];
            }
        }
    }
}

// Fused Q/K/V projection on the 256-tile core.  grid (64,1,3).
__global__ __launch_bounds__(512, 1) void g256qkv(
    const __bf16* __restrict__ Xn, const __bf16* __restrict__ Yn,
    const __bf16* __restrict__ WqT, const __bf16* __restrict__ WkT,
    const __bf16* __restrict__ WvT,
    const float* __restrict__ bq, const float* __restrict__ bk,
    const float* __restrict__ bv,
    __bf16* __restrict__ Qbf, __bf16* __restrict__ Kbf,
    __bf16* __restrict__ Vt)
{
    __shared__ __bf16 SA[4][256][32];
    __shared__ __bf16 SB[4][256][32];
    const int z = blockIdx.z;
    const __bf16* A    = (z == 0) ? Xn  : Yn;
    const __bf16* Bt   = (z == 0) ? WqT : (z == 1) ? WkT : WvT;
    const float*  bias = (z == 0) ? bq  : (z == 1) ? bk  : bv;

    int m0, n0;
    g256_decode<4>(blockIdx.x, 64, m0, n0);

    floatx4 acc[8][4] = {};
    g256_loop(A, Bt, DM, 0, m0, n0, &SA[0][0][0], &SB[0][0][0], acc);

    const int tid = threadIdx.x, lane = tid & 63, wave = tid >> 6;
    const int g = lane >> 4, c = lane & 15;
    const int wm = wave >> 2, wn = wave & 3;

#pragma unroll
    for (int i = 0; i < 8; i++) {
#pragma unroll
        for (int jj = 0; jj < 4; jj++) {
            const int row = m0 + wm * 128 + i * 16 + g * 4;
            const int col = n0 + wn * 64 + jj * 16 + c;
            const float bb = bias[col];
            float xs[4];
#pragma unroll
            for (int rr = 0; rr < 4; rr++) xs[rr] = acc[i][jj][rr] + bb;
            if (z == 0) {
#pragma unroll
                for (int rr = 0; rr < 4; rr++)
                    Qbf[(size_t)(row + rr) * DM + col] = (__bf16)xs[rr];
            } else if (z == 1) {
#pragma unroll
                for (int rr = 0; rr < 4; rr++) {
                    const int r2 = row + rr;
                    Kbf[(size_t)(r2 + (r2 >> 11)) * DM + col] = (__bf16)xs[rr];
                }
            } else {
                const int b  = row >> 11;
                const int kv = row & 2047;
                const size_t base =
                    ((size_t)((b * NH + (col >> 6)) * DHD + (col & 63))) * 2056 + kv;
                bf16x4 pk;
                pk[0] = (__bf16)xs[0]; pk[1] = (__bf16)xs[1];
                pk[2] = (__bf16)xs[2]; pk[3] = (__bf16)xs[3];
                *(bf16x4*)(Vt + base) = pk;
            }
        }
    }
}

// ---------------------------------------------------------------------------
// FF2 split-K reduction: out = sum_z partials[z] + bias + Hres.  float4/thread.
// ---------------------------------------------------------------------------
__global__ __launch_bounds__(256) void ff2_reduce(
    const float* __restrict__ part, const float* __restrict__ bias,
    const float* __restrict__ Hres, float* __restrict__ out)
{
    const size_t f4 = (size_t)blockIdx.x * 256 + threadIdx.x;  // float4 index
    const int c4 = (int)(f4 & (DM / 4 - 1));
    const size_t stride4 = (size_t)ROWS * DM / 4;
    float4 a = ((const float4*)part)[f4];
    const float4 p1 = ((const float4*)part)[f4 + stride4];
    const float4 p2 = ((const float4*)part)[f4 + 2 * stride4];
    const float4 p3 = ((const float4*)part)[f4 + 3 * stride4];
    const float4 b  = ((const float4*)bias)[c4];
    const float4 hr = ((const float4*)Hres)[f4];
    a.x += p1.x + p2.x + p3.x + b.x + hr.x;
    a.y += p1.y + p2.y + p3.y + b.y + hr.y;
    a.z += p1.z + p2.z + p3.z + b.z + hr.z;
    a.w += p1.w + p2.w + p3.w + b.w + hr.w;
    ((float4*)out)[f4] = a;
}

// ---------------------------------------------------------------------------
// Flash attention (round-6/7 proven): 128 q/block, 32 q/wave; gld_lds
// XOR-swizzled staging; 4-slot ring, 2 tiles per barrier; v_perm pack;
// ones-MFMA denominator; XCD-local heads.
// ---------------------------------------------------------------------------
__global__ __launch_bounds__(256, 2) void attn_kernel(
    const __bf16* __restrict__ Q, const __bf16* __restrict__ Kb,
    const __bf16* __restrict__ Vt, __bf16* __restrict__ O)
{
    __shared__ __bf16 Ks[4][64][64];   // [kv][d]   32 KB
    __shared__ __bf16 Vs[4][64][64];   // [d][kv]   32 KB

    const int tid = threadIdx.x, lane = tid & 63, w = tid >> 6;
    const int g = lane >> 4, c = lane & 15;

    const int hw   = blockIdx.x;
    const int slot = hw >> 3;
    const int hb   = (hw & 7) | ((slot >> 4) << 3);   // 0..31
    const int h = hb & 15, b = hb >> 4;
    const int q0w = (slot & 15) * 128 + w * 32;

    const float QSC = 0.03125f * 1.44269504088896f;
    bf16x8 qf[2][2];
#pragma unroll
    for (int qt = 0; qt < 2; qt++) {
        const __bf16* Qbase = Q + ((size_t)(b * NQS + q0w + qt * 16 + c)) * DM + h * DHD;
        qf[qt][0] = *(const bf16x8*)(Qbase + g * 8);
        qf[qt][1] = *(const bf16x8*)(Qbase + 32 + g * 8);
#pragma unroll
        for (int e = 0; e < 8; e++) {
            qf[qt][0][e] = (__bf16)((float)qf[qt][0][e] * QSC);
            qf[qt][1][e] = (__bf16)((float)qf[qt][1][e] * QSC);
        }
    }

    // ones fragment for the denominator MFMA (bf16 1.0 = 0x3F80)
    shortx4 ones;
    ones[0] = ones[1] = ones[2] = ones[3] = (short)0x3F80;

    floatx4 dacc[2] = {};        // denominator accumulators (rows identical)
    floatx4 oacc[2][4] = {};

    const int srow = tid >> 3;                    // LDS row 0..31 (and +32)
    const int schk = (tid & 7) ^ (srow & 7);      // swizzled 16B source chunk
    const __bf16* Kg  = Kb + (size_t)b * NKV1 * DM + h * DHD + schk * 8;
    const __bf16* Vg  = Vt + ((size_t)(b * NH + h) * DHD + srow) * 2056;
    const __bf16* Vg2 = Vg + (size_t)32 * 2056;
    const int vcol0 = schk * 8;

    auto stage = [&](int p, int kv0, bool tail) {
        __bf16* kd0 = &Ks[p][0][0]  + tid * 8;
        __bf16* kd1 = &Ks[p][32][0] + tid * 8;
        __bf16* vd0 = &Vs[p][0][0]  + tid * 8;
        __bf16* vd1 = &Vs[p][32][0] + tid * 8;
        if (!tail) {
            gld_lds16(Kg + (size_t)(kv0 + srow) * DM, kd0);
            gld_lds16(Kg + (size_t)(kv0 + srow + 32) * DM, kd1);
            gld_lds16(Vg + kv0 + vcol0, vd0);
            gld_lds16(Vg2 + kv0 + vcol0, vd1);
        } else {
            const int r0 = min(kv0 + srow, NKVS);
            const int r1 = min(kv0 + srow + 32, NKVS);
            const int vc = min(kv0 + vcol0, NKVS);
            gld_lds16(Kg + (size_t)r0 * DM, kd0);
            gld_lds16(Kg + (size_t)r1 * DM, kd1);
            gld_lds16(Vg + vc, vd0);
            gld_lds16(Vg2 + vc, vd1);
        }
    };

    auto compute = [&](int p, int kv0, bool tail) {
        floatx4 s[2][4];
#pragma unroll
        for (int qt = 0; qt < 2; qt++)
#pragma unroll
            for (int kvt = 0; kvt < 4; kvt++)
#pragma unroll
                for (int r = 0; r < 4; r++) s[qt][kvt][r] = -6.0f;

        const int sw = c & 7;
        __builtin_amdgcn_s_setprio(1);
#pragma unroll
        for (int kvt = 0; kvt < 4; kvt++) {
            const bf16x8 kf0 = *(const bf16x8*)&Ks[p][kvt * 16 + c][(g ^ sw) * 8];
            const bf16x8 kf1 = *(const bf16x8*)&Ks[p][kvt * 16 + c][((4 | g) ^ sw) * 8];
#pragma unroll
            for (int qt = 0; qt < 2; qt++) {
                s[qt][kvt] = __builtin_amdgcn_mfma_f32_16x16x32_bf16(kf0, qf[qt][0], s[qt][kvt], 0, 0, 0);
                s[qt][kvt] = __builtin_amdgcn_mfma_f32_16x16x32_bf16(kf1, qf[qt][1], s[qt][kvt], 0, 0, 0);
            }
        }
        __builtin_amdgcn_s_setprio(0);

        if (tail) {
#pragma unroll
            for (int qt = 0; qt < 2; qt++)
#pragma unroll
                for (int kvt = 0; kvt < 4; kvt++)
#pragma unroll
                    for (int r = 0; r < 4; r++)
                        if (kv0 + kvt * 16 + g * 4 + r >= NKV1) s[qt][kvt][r] = -1e30f;
        }

        // p = exp2(s); pack to bf16 by truncation via v_perm (1 op per word)
        shortx4 pf[2][4];
#pragma unroll
        for (int qt = 0; qt < 2; qt++)
#pragma unroll
            for (int kvt = 0; kvt < 4; kvt++) {
                const unsigned u0 = __builtin_bit_cast(unsigned, __builtin_amdgcn_exp2f(s[qt][kvt][0]));
                const unsigned u1 = __builtin_bit_cast(unsigned, __builtin_amdgcn_exp2f(s[qt][kvt][1]));
                const unsigned u2 = __builtin_bit_cast(unsigned, __builtin_amdgcn_exp2f(s[qt][kvt][2]));
                const unsigned u3 = __builtin_bit_cast(unsigned, __builtin_amdgcn_exp2f(s[qt][kvt][3]));
                unsigned pk0 = __builtin_amdgcn_perm(u1, u0, 0x07060302u);
                unsigned pk1 = __builtin_amdgcn_perm(u3, u2, 0x07060302u);
                unsigned long long pk = ((unsigned long long)pk1 << 32) | pk0;
                pf[qt][kvt] = __builtin_bit_cast(shortx4, pk);
            }

        // O^T += V^T P^T ; denominator via ones-row MFMA
        __builtin_amdgcn_s_setprio(1);
#pragma unroll
        for (int kvt = 0; kvt < 4; kvt++) {
            shortx4 vfr[4];
#pragma unroll
            for (int dt = 0; dt < 4; dt++) {
                const int slotp = (kvt * 2 + (g >> 1)) ^ sw;
                vfr[dt] = *(const shortx4*)&Vs[p][dt * 16 + c][slotp * 8 + (g & 1) * 4];
            }
#pragma unroll
            for (int dt = 0; dt < 4; dt++)
#pragma unroll
                for (int qt = 0; qt < 2; qt++)
                    oacc[qt][dt] = __builtin_amdgcn_mfma_f32_16x16x16bf16_1k(
                        vfr[dt], pf[qt][kvt], oacc[qt][dt], 0, 0, 0);
#pragma unroll
            for (int qt = 0; qt < 2; qt++)
                dacc[qt] = __builtin_amdgcn_mfma_f32_16x16x16bf16_1k(
                    ones, pf[qt][kvt], dacc[qt], 0, 0, 0);
        }
        __builtin_amdgcn_s_setprio(0);
    };

    // 4-slot ring, 2 tiles per barrier period.  Tiles 0..32 (32 = tail).
    stage(0, 0, false);
    stage(1, 64, false);
    __syncthreads();
    for (int it = 0; it < 32; it += 2) {
        stage((it + 2) & 3, (it + 2) * 64, (it + 2) == 32);
        if (it + 3 <= 32) stage((it + 3) & 3, (it + 3) * 64, false);
        compute(it & 3, it * 64, false);
        compute((it + 1) & 3, (it + 1) * 64, false);
        __syncthreads();                 // staged tiles visible; reads done
    }
    compute(0, 2048, true);              // tail tile (32) in slot 0

#pragma unroll
    for (int qt = 0; qt < 2; qt++) {
        const float inv_l = 1.0f / dacc[qt][0];
        __bf16* Ob = O + ((size_t)(b * NQS + q0w + qt * 16 + c)) * DM + h * DHD;
#pragma unroll
        for (int dt = 0; dt < 4; dt++) {
            bf16x4 ob;
#pragma unroll
            for (int r = 0; r < 4; r++) ob[r] = (__bf16)(oacc[qt][dt][r] * inv_l);
            *(bf16x4*)(Ob + dt * 16 + g * 4) = ob;
        }
    }
}

// ---------------------------------------------------------------------------
extern "C" void kernel_launch(void* const* d_in, const int* in_sizes, int n_in,
                              void* d_out, int out_size, void* d_ws, size_t ws_size,
                              hipStream_t stream)
{
    const float* X      = (const float*)d_in[0];
    const float* Y      = (const float*)d_in[1];
    const float* Wq     = (const float*)d_in[2];
    const float* bq     = (const float*)d_in[3];
    const float* Wk     = (const float*)d_in[4];
    const float* bk     = (const float*)d_in[5];
    const float* Wv     = (const float*)d_in[6];
    const float* bv     = (const float*)d_in[7];
    const float* null_k = (const float*)d_in[8];
    const float* g0     = (const float*)d_in[9];
    const float* b0     = (const float*)d_in[10];
    const float* g0kv   = (const float*)d_in[11];
    const float* b0kv   = (const float*)d_in[12];
    const float* g1     = (const float*)d_in[13];
    const float* b1     = (const float*)d_in[14];
    const float* W1     = (const float*)d_in[15];
    const float* bf1    = (const float*)d_in[16];
    const float* W2     = (const float*)d_in[17];
    const float* bf2    = (const float*)d_in[18];
    float* out = (float*)d_out;

    // workspace carve (bytes).  Persistent-through-FF2 buffers FIRST so the
    // tail region (dead by FF2 time) can be reused for split-K partials.
    char* p = (char*)d_ws;
    __bf16* W2T  = (__bf16*)p; p += (size_t)4 * DM * DM * 2;          // [1024][4096]
    float*  Hres = (float*)p;  p += (size_t)ROWS * DM * 4;
    __bf16* Gbf  = (__bf16*)p; p += (size_t)ROWS * 4 * DM * 2;
    char* scratch = p;                                                // dead by FF2
    __bf16* Xn   = (__bf16*)p; p += (size_t)ROWS * DM * 2;
    __bf16* Yn   = (__bf16*)p; p += (size_t)ROWS * DM * 2;
    __bf16* WqT  = (__bf16*)p; p += (size_t)DM * DM * 2;
    __bf16* WkT  = (__bf16*)p; p += (size_t)DM * DM * 2;
    __bf16* WvT  = (__bf16*)p; p += (size_t)DM * DM * 2;
    __bf16* W1T  = (__bf16*)p; p += (size_t)4 * DM * DM * 2;          // [4096][1024]
    __bf16* Qbf  = (__bf16*)p; p += (size_t)ROWS * DM * 2;
    __bf16* Kbf  = (__bf16*)p; p += (size_t)BATCH * NKV1 * DM * 2;
    __bf16* Vt   = (__bf16*)p; p += (size_t)BATCH * NH * DHD * 2056 * 2;
    __bf16* Obf  = (__bf16*)p; p += (size_t)ROWS * DM * 2;
    __bf16* Hr   = (__bf16*)p; p += (size_t)ROWS * DM * 2;
    float* Part  = (float*)scratch;  // FF2 partials: 4 x ROWS x DM f32 = 67 MB

    // 1. LayerNorms (fused X+Y, one launch)
    ln2_to_bf16<<<2 * ROWS, 256, 0, stream>>>(X, Y, g0, b0, g0kv, b0kv, Xn, Yn);

    // 2. weight transposes (f32 -> bf16, W^T), two launches total
    transpose3_f32_bf16<<<dim3(DM / 32, DM / 32, 3), dim3(32, 8), 0, stream>>>(
        Wq, Wk, Wv, WqT, WkT, WvT);
    transpose_ffw<<<dim3(128, 32, 2), dim3(32, 8), 0, stream>>>(W1, W2, W1T, W2T);

    // 3. fused Q/K/V projections on the 2-phase 256-tile core
    g256qkv<<<dim3(64, 1, 3), 512, 0, stream>>>(
        Xn, Yn, WqT, WkT, WvT, bq, bk, bv, Qbf, Kbf, Vt);
    fill_null<<<64, 256, 0, stream>>>(null_k, Kbf, Vt);

    // 4. attention (4-slot ring, 2 tiles/barrier, XCD-local heads)
    attn_kernel<<<dim3(512), 256, 0, stream>>>(Qbf, Kbf, Vt, Obf);

    // 5. residual + LN
    resid_ln<<<ROWS, 256, 0, stream>>>(X, Obf, g1, b1, Hres, Hr);

    // 6. FFN: FF1 (bf16 + GELU), FF2 split-K=4 partials, then reduce
    g256<0, 1, 16><<<dim3(256), 512, 0, stream>>>(
        Hr, W1T, bf1, (void*)Gbf, ROWS, 4 * DM, DM);
    g256<4, 0, 4><<<dim3(64, 1, 4), 512, 0, stream>>>(
        Gbf, W2T, bf2, (void*)Part, ROWS, DM, 4 * DM);
    ff2_reduce<<<ROWS * DM / 1024, 256, 0, stream>>>(Part, bf2, Hres, out);
}